// Round 8
// baseline (572.099 us; speedup 1.0000x reference)
//
#include <hip/hip_runtime.h>

// GSModel pipeline, round 8.
//  - p_b = sum(g1_b) - sum(g2_b) identity (sinkhorn colsum==1) — scores path removed.
//  - bf16 storage; MFMA 16x16x32 bf16, XOR-swizzled LDS; fused gather+GEMM1+GEMM2 layer.
//  - NEW: chunk-bucketed CSR. Each node's neighbor list is stored as 4 segments
//    bucketed by source-row chunk (8192 rows = 4MB table window). The fused
//    gather loops chunks at block level -> per-phase working set fits one XCD L2.
//    Each edge visited exactly once (reorder only) — no round-5 instruction tax.
//  - stageW(w1) hoisted before gather; h ping-pong buffers.

constexpr int NNODE = 32768;
constexpr int NEDGE = 524288;

typedef __attribute__((ext_vector_type(8))) short bf16x8;
typedef __attribute__((ext_vector_type(4))) float f32x4;

__device__ __forceinline__ float bf2f(unsigned short u) {
  return __uint_as_float((unsigned)u << 16);
}
__device__ __forceinline__ unsigned short f2bf(float f) {
  unsigned u = __float_as_uint(f);
  return (unsigned short)((u + 0x7FFFu + ((u >> 16) & 1u)) >> 16);
}
__device__ __forceinline__ unsigned packbf(float a, float b) {
  return (unsigned)f2bf(a) | ((unsigned)f2bf(b) << 16);
}

// ---------------- feature convert f32 -> bf16 ----------------
__global__ __launch_bounds__(256) void k_conv(const float* __restrict__ a,
                                              const float* __restrict__ b,
                                              unsigned short* __restrict__ out) {
  size_t i = (size_t)blockIdx.x * 256 + threadIdx.x;   // 4,194,304 chunks of 4
  const float* src = (i < 2097152) ? (a + i * 4) : (b + (i - 2097152) * 4);
  float4 v = *(const float4*)src;
  ushort4 o;
  o.x = f2bf(v.x); o.y = f2bf(v.y); o.z = f2bf(v.z); o.w = f2bf(v.w);
  *(ushort4*)(out + i * 4) = o;
}

// ---------------- weight transpose + convert: Wt[n][k] = W[k][n], bf16 ----------------
__global__ __launch_bounds__(256) void k_wprep(const float* __restrict__ gw1,
                                               const float* __restrict__ gw2,
                                               unsigned short* __restrict__ Wt) {
  __shared__ float sh[64][65];
  int b = blockIdx.x;            // 96 = 6 mats x 16 tiles of 64x64
  int mat = b >> 4, tile = b & 15;
  int tr = (tile >> 2) * 64, tc = (tile & 3) * 64;
  const float* src = (mat < 3) ? (gw1 + (size_t)mat * 65536) : (gw2 + (size_t)(mat - 3) * 65536);
  int t = threadIdx.x;
#pragma unroll
  for (int i = 0; i < 4; i++) {
    int c = t + i * 256;         // 1024 float4 chunks
    int row = c >> 4, c4 = (c & 15) * 4;
    float4 v = *(const float4*)(src + (size_t)(tr + row) * 256 + tc + c4);
    sh[row][c4] = v.x; sh[row][c4 + 1] = v.y; sh[row][c4 + 2] = v.z; sh[row][c4 + 3] = v.w;
  }
  __syncthreads();
#pragma unroll
  for (int i = 0; i < 2; i++) {
    int c = t + i * 256;         // 512 chunks of 8 bf16
    int n = c >> 3, kc = (c & 7) * 8;
    unsigned short e[8];
#pragma unroll
    for (int j = 0; j < 8; j++) e[j] = f2bf(sh[kc + j][n]);
    uint4 o;
    o.x = e[0] | ((unsigned)e[1] << 16);
    o.y = e[2] | ((unsigned)e[3] << 16);
    o.z = e[4] | ((unsigned)e[5] << 16);
    o.w = e[6] | ((unsigned)e[7] << 16);
    *(uint4*)(Wt + (size_t)mat * 65536 + (size_t)(tc + n) * 256 + tr + kc) = o;
  }
}

// ---------------- CSR build, 4-way src-chunk buckets ----------------
__global__ void k_degree4(const int* __restrict__ e1, const int* __restrict__ e2,
                          int* __restrict__ cnt4) {
  int b = blockIdx.x;                 // 4096
  int side = b >> 11;
  int e = (b & 2047) * 256 + threadIdx.x;
  const int* ei = (side ? e2 : e1);
  int s = ei[e], d = ei[NEDGE + e];
  atomicAdd(&cnt4[((size_t)side * NNODE + d) * 4 + (s >> 13)], 1);
}

__global__ void k_scan2(const int* __restrict__ cnt4, int* __restrict__ off) {
  __shared__ int sh[1024];
  int side = blockIdx.x;              // grid 2
  const int* c4 = cnt4 + (size_t)side * NNODE * 4;
  int* of = off + side * (NNODE + 64);
  int t = threadIdx.x;
  int base = t * 32;
  int loc[32];
  int s = 0;
#pragma unroll
  for (int j = 0; j < 32; j++) {
    int n4 = (base + j) * 4;
    loc[j] = c4[n4] + c4[n4 + 1] + c4[n4 + 2] + c4[n4 + 3];
    s += loc[j];
  }
  sh[t] = s;
  __syncthreads();
  for (int d = 1; d < 1024; d <<= 1) {
    int v = (t >= d) ? sh[t - d] : 0;
    __syncthreads();
    sh[t] += v;
    __syncthreads();
  }
  int run = sh[t] - s;
#pragma unroll
  for (int j = 0; j < 32; j++) { of[base + j] = run; run += loc[j]; }
  if (t == 1023) of[NNODE] = run;
}

__global__ __launch_bounds__(256) void k_suboff(const int* __restrict__ cnt4,
                                                const int* __restrict__ off,
                                                int* __restrict__ off2,
                                                int* __restrict__ cur2) {
  int i = blockIdx.x * 256 + threadIdx.x;     // 0..65535
  int side = i >> 15, n = i & 32767;
  int base = off[side * (NNODE + 64) + n];
  size_t i4 = (size_t)i * 4;
  int c0 = cnt4[i4], c1 = cnt4[i4 + 1], c2 = cnt4[i4 + 2];
  int o0 = base, o1 = base + c0, o2 = o1 + c1, o3 = o2 + c2;
  off2[i4] = o0; off2[i4 + 1] = o1; off2[i4 + 2] = o2; off2[i4 + 3] = o3;
  cur2[i4] = o0; cur2[i4 + 1] = o1; cur2[i4 + 2] = o2; cur2[i4 + 3] = o3;
}

__global__ void k_scatter4(const int* __restrict__ e1, const int* __restrict__ e2,
                           int* __restrict__ cur2, int* __restrict__ srcs) {
  int b = blockIdx.x;                 // 4096
  int side = b >> 11;
  int e = (b & 2047) * 256 + threadIdx.x;
  const int* ei = (side ? e2 : e1);
  int s = ei[e], d = ei[NEDGE + e];
  int p = atomicAdd(&cur2[((size_t)side * NNODE + d) * 4 + (s >> 13)], 1);
  srcs[(size_t)side * NEDGE + p] = s;
}

// ---------------- fused layer: gather(+BN) -> GEMM1(relu) -> GEMM2 + stats ----------------
// grid 1024 (2 sides x 512 row-blocks of 64), 512 thr = 8 waves (2m x 4n).
// LDS 68KB: sA/sA2 [64][512B] at [0,32K), sW [256][128B] at [32K,64K), red 4K at [64K,68K).
// Gather: half-wave owns 4 node rows, chunk-outer loop (4MB L2-resident window/phase).
template <bool BN>
__global__ __launch_bounds__(512, 4) void k_layer(
    const unsigned short* __restrict__ x,      // [2N][256] prev features
    const int* __restrict__ off,               // [2][NNODE+64] totals
    const int* __restrict__ off2,              // [2][NNODE][4] bucket starts
    const int* __restrict__ srcs,
    const float* __restrict__ pstats,          // [2][2][256] prev layer (BN only)
    const float* __restrict__ pgamma, const float* __restrict__ pbeta,
    const unsigned short* __restrict__ w1t,    // [256][256] bf16 transposed
    const unsigned short* __restrict__ w2t,
    const float* __restrict__ b1, const float* __restrict__ b2,
    float* __restrict__ stats,                 // [2][2][256] this layer
    unsigned short* __restrict__ hout) {
  __shared__ __align__(16) char smem[69632];
  char* sA = smem;                 // [64][512B] swizzled bf16 (gather out / phase1 A / phase2 A)
  char* sA2 = smem;                // alias
  char* sW = smem + 32768;         // [256][128B] swizzled W chunk; later h bounce
  float2* red = (float2*)(smem + 65536);
  int tid = threadIdx.x;
  int lane = tid & 63, wid = tid >> 6;
  int wm = wid & 1, wn = wid >> 1;
  int q = lane >> 4, r = lane & 15;
  const int sw = (r & 7) << 4;
  int b = blockIdx.x;
  int side = b >> 9;
  size_t grow0 = (size_t)side * NNODE + (size_t)(b & 511) * 64;

  auto stageW = [&](const unsigned short* wsrc, int k0) {
    for (int c = tid; c < 2048; c += 512) {
      int row = c >> 3, cb = (c & 7) * 16;
      float4 v = *(const float4*)(wsrc + (size_t)row * 256 + k0 + (c & 7) * 8);
      *(float4*)(sW + row * 128 + (cb ^ ((row & 7) << 4))) = v;
    }
  };

  stageW(w1t, 0);   // hoisted: loads overlap gather

  // ============ gather phase: aggregate 64 rows into sA ============
  {
    int hw = tid >> 5, sub = tid & 31;       // half-wave owns 4 node rows
    float sc[8], shf[8];
    if (BN) {
      int c0 = sub * 8;
      const float* cs = pstats + side * 512;
      const float invn = 1.f / 32768.f;
#pragma unroll
      for (int j = 0; j < 8; j++) {
        float mu = cs[c0 + j] * invn;
        float var = cs[256 + c0 + j] * invn - mu * mu;
        float s = pgamma[c0 + j] * rsqrtf(var + 1e-5f);
        sc[j] = s; shf[j] = pbeta[c0 + j] - mu * s;
      }
    }
    const uint4* X = (const uint4*)x;        // 32 uint4 per row
    size_t rbase = (size_t)side * NNODE;
    const int* offs = off + side * (NNODE + 64);
    const int* offs2 = off2 + (size_t)side * NNODE * 4;
    const int* sr = srcs + (size_t)side * NEDGE;
    int nbase = (int)(b & 511) * 64 + hw * 4;

    float a[4][8];
#pragma unroll
    for (int nn = 0; nn < 4; nn++)
#pragma unroll
      for (int j = 0; j < 8; j++) a[nn][j] = 0.f;

    auto acc8 = [&](float* ap, uint4 u, float w) {
      unsigned uu[4] = {u.x, u.y, u.z, u.w};
#pragma unroll
      for (int j = 0; j < 4; j++) {
        float lo = __uint_as_float(uu[j] << 16);
        float hi = __uint_as_float(uu[j] & 0xFFFF0000u);
        if (BN) {
          lo = fmaxf(fmaf(lo, sc[2 * j], shf[2 * j]), 0.f);
          hi = fmaxf(fmaf(hi, sc[2 * j + 1], shf[2 * j + 1]), 0.f);
        }
        ap[2 * j] = fmaf(lo, w, ap[2 * j]);
        ap[2 * j + 1] = fmaf(hi, w, ap[2 * j + 1]);
      }
    };

    // self terms (weight 2), sequential rows — trivially cached
#pragma unroll
    for (int nn = 0; nn < 4; nn++)
      acc8(a[nn], X[(rbase + nbase + nn) * 32 + sub], 2.f);

    // chunk-outer edge loops: per phase the gather window is 4MB (L2-resident)
#pragma unroll 1
    for (int c = 0; c < 4; c++) {
#pragma unroll
      for (int nn = 0; nn < 4; nn++) {
        int n = nbase + nn;
        int e = offs2[(n << 2) + c];
        int ee = (c < 3) ? offs2[(n << 2) + c + 1] : offs[n + 1];
        for (; e + 3 < ee; e += 4) {
          int i0 = sr[e], i1 = sr[e + 1], i2 = sr[e + 2], i3 = sr[e + 3];
          uint4 u0 = X[(rbase + i0) * 32 + sub];
          uint4 u1 = X[(rbase + i1) * 32 + sub];
          uint4 u2 = X[(rbase + i2) * 32 + sub];
          uint4 u3 = X[(rbase + i3) * 32 + sub];
          acc8(a[nn], u0, 1.f); acc8(a[nn], u1, 1.f);
          acc8(a[nn], u2, 1.f); acc8(a[nn], u3, 1.f);
        }
        for (; e < ee; e++) acc8(a[nn], X[(rbase + sr[e]) * 32 + sub], 1.f);
      }
    }

#pragma unroll
    for (int nn = 0; nn < 4; nn++) {
      int lrow = hw * 4 + nn;
      uint4 o;
      o.x = packbf(a[nn][0], a[nn][1]); o.y = packbf(a[nn][2], a[nn][3]);
      o.z = packbf(a[nn][4], a[nn][5]); o.w = packbf(a[nn][6], a[nn][7]);
      *(uint4*)(sA + lrow * 512 + ((sub * 16) ^ ((lrow & 7) << 4))) = o;
    }
  }

  f32x4 acc[2][4];
#pragma unroll
  for (int mi = 0; mi < 2; mi++)
#pragma unroll
    for (int ni = 0; ni < 4; ni++) acc[mi][ni] = (f32x4){0.f, 0.f, 0.f, 0.f};

  __syncthreads();

  // ---- phase 1: C1 = A @ W1 ----
  for (int k0 = 0; k0 < 256; k0 += 64) {
#pragma unroll
    for (int ks = 0; ks < 2; ks++) {
      bf16x8 af[2], bfr[4];
      int cbA = (k0 * 2 + ks * 64 + q * 16) ^ sw;
      int cbW = (ks * 64 + q * 16) ^ sw;
#pragma unroll
      for (int mi = 0; mi < 2; mi++)
        af[mi] = *(const bf16x8*)(sA + (wm * 32 + mi * 16 + r) * 512 + cbA);
#pragma unroll
      for (int ni = 0; ni < 4; ni++)
        bfr[ni] = *(const bf16x8*)(sW + (wn * 64 + ni * 16 + r) * 128 + cbW);
#pragma unroll
      for (int mi = 0; mi < 2; mi++)
#pragma unroll
        for (int ni = 0; ni < 4; ni++)
          acc[mi][ni] = __builtin_amdgcn_mfma_f32_16x16x32_bf16(af[mi], bfr[ni], acc[mi][ni], 0, 0, 0);
    }
    __syncthreads();
    if (k0 < 192) {
      stageW(w1t, k0 + 64);
      __syncthreads();
    }
  }

  // epilogue 1: bias + relu -> bf16 into sA2 (alias of sA; all reads done)
  float b1v[4];
#pragma unroll
  for (int ni = 0; ni < 4; ni++) b1v[ni] = b1[wn * 64 + ni * 16 + r];
#pragma unroll
  for (int mi = 0; mi < 2; mi++)
#pragma unroll
    for (int ni = 0; ni < 4; ni++)
#pragma unroll
      for (int j = 0; j < 4; j++) {
        float o = fmaxf(acc[mi][ni][j] + b1v[ni], 0.f);
        int rowc = wm * 32 + mi * 16 + q * 4 + j;
        int colc = wn * 64 + ni * 16 + r;
        *(unsigned short*)(sA2 + rowc * 512 + ((colc * 2) ^ (((q * 4 + j) & 7) << 4))) = f2bf(o);
      }
#pragma unroll
  for (int mi = 0; mi < 2; mi++)
#pragma unroll
    for (int ni = 0; ni < 4; ni++) acc[mi][ni] = (f32x4){0.f, 0.f, 0.f, 0.f};
  stageW(w2t, 0);
  __syncthreads();

  // ---- phase 2: C2 = relu(C1) @ W2 ----
  for (int k0 = 0; k0 < 256; k0 += 64) {
#pragma unroll
    for (int ks = 0; ks < 2; ks++) {
      bf16x8 af[2], bfr[4];
      int cbA = (k0 * 2 + ks * 64 + q * 16) ^ sw;
      int cbW = (ks * 64 + q * 16) ^ sw;
#pragma unroll
      for (int mi = 0; mi < 2; mi++)
        af[mi] = *(const bf16x8*)(sA2 + (wm * 32 + mi * 16 + r) * 512 + cbA);
#pragma unroll
      for (int ni = 0; ni < 4; ni++)
        bfr[ni] = *(const bf16x8*)(sW + (wn * 64 + ni * 16 + r) * 128 + cbW);
#pragma unroll
      for (int mi = 0; mi < 2; mi++)
#pragma unroll
        for (int ni = 0; ni < 4; ni++)
          acc[mi][ni] = __builtin_amdgcn_mfma_f32_16x16x32_bf16(af[mi], bfr[ni], acc[mi][ni], 0, 0, 0);
    }
    __syncthreads();
    if (k0 < 192) {
      stageW(w2t, k0 + 64);
      __syncthreads();
    }
  }

  // epilogue 2: bias, BN stats, bf16 out via sW bounce (sW dead after phase 2)
  float b2v[4];
#pragma unroll
  for (int ni = 0; ni < 4; ni++) b2v[ni] = b2[wn * 64 + ni * 16 + r];
#pragma unroll
  for (int ni = 0; ni < 4; ni++) {
    float ss = 0.f, sq = 0.f;
#pragma unroll
    for (int mi = 0; mi < 2; mi++)
#pragma unroll
      for (int j = 0; j < 4; j++) {
        float o = acc[mi][ni][j] + b2v[ni];
        acc[mi][ni][j] = o;
        ss += o; sq += o * o;
      }
    ss += __shfl_xor(ss, 16, 64); ss += __shfl_xor(ss, 32, 64);
    sq += __shfl_xor(sq, 16, 64); sq += __shfl_xor(sq, 32, 64);
    if (q == 0) {
      float2 w; w.x = ss; w.y = sq;
      red[(wn * 64 + ni * 16 + r) * 2 + wm] = w;
    }
  }
#pragma unroll
  for (int mi = 0; mi < 2; mi++)
#pragma unroll
    for (int ni = 0; ni < 4; ni++)
#pragma unroll
      for (int j = 0; j < 4; j++) {
        int rowc = wm * 32 + mi * 16 + q * 4 + j;
        int colc = wn * 64 + ni * 16 + r;
        *(unsigned short*)(sW + rowc * 512 + ((colc * 2) ^ (((q * 4 + j) & 7) << 4))) =
            f2bf(acc[mi][ni][j]);
      }
  __syncthreads();
  float* cs = stats + side * 512;
  if (tid < 256) {
    float2 a = red[tid * 2], c2 = red[tid * 2 + 1];
    atomicAdd(&cs[tid], a.x + c2.x);
    atomicAdd(&cs[256 + tid], a.y + c2.y);
  }
  for (int c = tid; c < 2048; c += 512) {   // 64 rows x 32 chunks of 16B
    int row = c >> 5, cb = (c & 31) * 16;
    float4 v = *(const float4*)(sW + row * 512 + (cb ^ ((row & 7) << 4)));
    *(float4*)(hout + (grow0 + row) * 256 + (c & 31) * 8) = v;
  }
}

// ---------------- per-graph sum of relu(bn(h)) ----------------
__global__ __launch_bounds__(256) void k_gsum(
    const unsigned short* __restrict__ h, const float* __restrict__ stats,
    const float* __restrict__ gamma, const float* __restrict__ beta,
    float* __restrict__ sg) {
  int b = blockIdx.x;            // 256 = 2 sides x 128 graphs
  int side = b >> 7, g = b & 127;
  int t = threadIdx.x;
  int c0 = (t & 63) * 4, rg = t >> 6;
  const float* cs = stats + side * 512;
  float sc[4], sh_[4];
#pragma unroll
  for (int j = 0; j < 4; j++) {
    float mu = cs[c0 + j] * (1.f / 32768.f);
    float var = cs[256 + c0 + j] * (1.f / 32768.f) - mu * mu;
    float s = gamma[c0 + j] * rsqrtf(var + 1e-5f);
    sc[j] = s; sh_[j] = beta[c0 + j] - mu * s;
  }
  size_t base = (size_t)side * NNODE + (size_t)g * 256;
  float acc = 0.f;
  for (int k = 0; k < 64; k++) {
    int row = rg + k * 4;
    ushort4 u = *(const ushort4*)(h + (base + row) * 256 + c0);
    acc += fmaxf(fmaf(bf2f(u.x), sc[0], sh_[0]), 0.f);
    acc += fmaxf(fmaf(bf2f(u.y), sc[1], sh_[1]), 0.f);
    acc += fmaxf(fmaf(bf2f(u.z), sc[2], sh_[2]), 0.f);
    acc += fmaxf(fmaf(bf2f(u.w), sc[3], sh_[3]), 0.f);
  }
  __shared__ float red[256];
  red[t] = acc;
  __syncthreads();
  if (t < 64) {
    float s = red[t] + red[t + 64] + red[t + 128] + red[t + 192];
#pragma unroll
    for (int m = 1; m < 64; m <<= 1) s += __shfl_xor(s, m, 64);
    if (t == 0) sg[b] = s;
  }
}

// ---------------- final: p = sg1 - sg2, min-max normalize, exp(-p) ----------------
__global__ void k_final(const float* __restrict__ sg1, const float* __restrict__ sg2,
                        float* __restrict__ out) {
  int t = threadIdx.x;   // 64 threads
  float a = sg1[t] - sg2[t];
  float b = sg1[t + 64] - sg2[t + 64];
  float mn = fminf(a, b), mx = fmaxf(a, b);
#pragma unroll
  for (int msk = 1; msk < 64; msk <<= 1) {
    mn = fminf(mn, __shfl_xor(mn, msk, 64));
    mx = fmaxf(mx, __shfl_xor(mx, msk, 64));
  }
  float inv = 1.0f / (mx - mn);
  out[t] = __expf(-(a - mn) * inv);
  out[t + 64] = __expf(-(b - mn) * inv);
}

// ---------------- host ----------------
extern "C" void kernel_launch(void* const* d_in, const int* in_sizes, int n_in,
                              void* d_out, int out_size, void* d_ws, size_t ws_size,
                              hipStream_t stream) {
  (void)in_sizes; (void)n_in; (void)out_size; (void)ws_size;
  const float* f1 = (const float*)d_in[0];
  const float* f2 = (const float*)d_in[1];
  const int* e1 = (const int*)d_in[2];
  const int* e2 = (const int*)d_in[3];
  const float* gw1 = (const float*)d_in[5];
  const float* gb1 = (const float*)d_in[6];
  const float* gw2 = (const float*)d_in[7];
  const float* gb2 = (const float*)d_in[8];
  const float* gga = (const float*)d_in[9];
  const float* gbe = (const float*)d_in[10];
  float* out = (float*)d_out;

  char* ws = (char*)d_ws;
  size_t o = 0;
  auto alloc = [&](size_t bytes) { void* p = ws + o; o += (bytes + 255) & ~(size_t)255; return p; };
  unsigned short* hb0 = (unsigned short*)alloc(2ull * NNODE * 256 * 2);
  unsigned short* hb1 = (unsigned short*)alloc(2ull * NNODE * 256 * 2);
  unsigned short* Wt = (unsigned short*)alloc(6ull * 65536 * 2);
  float* stats = (float*)alloc(3 * 1024 * 4);      // [layer][side][{sum,sq}][256]
  float* sg = (float*)alloc(256 * 4);
  int* cnt4 = (int*)alloc(2ull * NNODE * 4 * 4);
  int* off = (int*)alloc(2 * (NNODE + 64) * 4);
  int* off2 = (int*)alloc(2ull * NNODE * 4 * 4);
  int* cur2 = (int*)alloc(2ull * NNODE * 4 * 4);
  int* srcs = (int*)alloc(2ull * NEDGE * 4);

  (void)hipMemsetAsync(stats, 0, 3 * 1024 * 4, stream);
  (void)hipMemsetAsync(cnt4, 0, 2ull * NNODE * 4 * 4, stream);

  k_conv<<<16384, 256, 0, stream>>>(f1, f2, hb0);
  k_wprep<<<96, 256, 0, stream>>>(gw1, gw2, Wt);
  k_degree4<<<4096, 256, 0, stream>>>(e1, e2, cnt4);
  k_scan2<<<2, 1024, 0, stream>>>(cnt4, off);
  k_suboff<<<256, 256, 0, stream>>>(cnt4, off, off2, cur2);
  k_scatter4<<<4096, 256, 0, stream>>>(e1, e2, cur2, srcs);

  unsigned short* hb[2] = {hb0, hb1};
  for (int l = 0; l < 3; l++) {
    unsigned short* xin = hb[l & 1];
    unsigned short* hout = hb[1 - (l & 1)];
    if (l == 0)
      k_layer<false><<<1024, 512, 0, stream>>>(
          xin, off, off2, srcs, nullptr, nullptr, nullptr,
          Wt + (size_t)l * 65536, Wt + (size_t)(3 + l) * 65536,
          gb1 + l * 256, gb2 + l * 256, stats + l * 1024, hout);
    else
      k_layer<true><<<1024, 512, 0, stream>>>(
          xin, off, off2, srcs, stats + (l - 1) * 1024, gga + (l - 1) * 256, gbe + (l - 1) * 256,
          Wt + (size_t)l * 65536, Wt + (size_t)(3 + l) * 65536,
          gb1 + l * 256, gb2 + l * 256, stats + l * 1024, hout);
  }

  k_gsum<<<256, 256, 0, stream>>>(hb1, stats + 2 * 1024, gga + 512, gbe + 512, sg);
  k_final<<<1, 64, 0, stream>>>(sg, sg + 128, out);
}

// Round 9
// 555.801 us; speedup vs baseline: 1.0293x; 1.0293x over previous
//
#include <hip/hip_runtime.h>

// GSModel pipeline, round 9.
//  - p_b = sum(g1_b) - sum(g2_b) identity (sinkhorn colsum==1) — scores path removed.
//  - bf16 storage; MFMA 16x16x32 bf16, XOR-swizzled LDS; fused gather+GEMM1+GEMM2.
//  - Round-8 bucketed CSR REVERTED (fragmented edge loops = instruction tax).
//  - NEW: 32-row tiles -> LDS 52KB -> 3 blocks/CU (24 waves, was 2x8=16):
//    gather concurrency +50%. Grid 2048, 512 thr = 8 waves (2m x 4n), wave tile 16x64.

constexpr int NNODE = 32768;
constexpr int NEDGE = 524288;

typedef __attribute__((ext_vector_type(8))) short bf16x8;
typedef __attribute__((ext_vector_type(4))) float f32x4;

__device__ __forceinline__ float bf2f(unsigned short u) {
  return __uint_as_float((unsigned)u << 16);
}
__device__ __forceinline__ unsigned short f2bf(float f) {
  unsigned u = __float_as_uint(f);
  return (unsigned short)((u + 0x7FFFu + ((u >> 16) & 1u)) >> 16);
}
__device__ __forceinline__ unsigned packbf(float a, float b) {
  return (unsigned)f2bf(a) | ((unsigned)f2bf(b) << 16);
}

// ---------------- feature convert f32 -> bf16 ----------------
__global__ __launch_bounds__(256) void k_conv(const float* __restrict__ a,
                                              const float* __restrict__ b,
                                              unsigned short* __restrict__ out) {
  size_t i = (size_t)blockIdx.x * 256 + threadIdx.x;   // 4,194,304 chunks of 4
  const float* src = (i < 2097152) ? (a + i * 4) : (b + (i - 2097152) * 4);
  float4 v = *(const float4*)src;
  ushort4 o;
  o.x = f2bf(v.x); o.y = f2bf(v.y); o.z = f2bf(v.z); o.w = f2bf(v.w);
  *(ushort4*)(out + i * 4) = o;
}

// ---------------- weight transpose + convert: Wt[n][k] = W[k][n], bf16 ----------------
__global__ __launch_bounds__(256) void k_wprep(const float* __restrict__ gw1,
                                               const float* __restrict__ gw2,
                                               unsigned short* __restrict__ Wt) {
  __shared__ float sh[64][65];
  int b = blockIdx.x;            // 96 = 6 mats x 16 tiles of 64x64
  int mat = b >> 4, tile = b & 15;
  int tr = (tile >> 2) * 64, tc = (tile & 3) * 64;
  const float* src = (mat < 3) ? (gw1 + (size_t)mat * 65536) : (gw2 + (size_t)(mat - 3) * 65536);
  int t = threadIdx.x;
#pragma unroll
  for (int i = 0; i < 4; i++) {
    int c = t + i * 256;         // 1024 float4 chunks
    int row = c >> 4, c4 = (c & 15) * 4;
    float4 v = *(const float4*)(src + (size_t)(tr + row) * 256 + tc + c4);
    sh[row][c4] = v.x; sh[row][c4 + 1] = v.y; sh[row][c4 + 2] = v.z; sh[row][c4 + 3] = v.w;
  }
  __syncthreads();
#pragma unroll
  for (int i = 0; i < 2; i++) {
    int c = t + i * 256;         // 512 chunks of 8 bf16
    int n = c >> 3, kc = (c & 7) * 8;
    unsigned short e[8];
#pragma unroll
    for (int j = 0; j < 8; j++) e[j] = f2bf(sh[kc + j][n]);
    uint4 o;
    o.x = e[0] | ((unsigned)e[1] << 16);
    o.y = e[2] | ((unsigned)e[3] << 16);
    o.z = e[4] | ((unsigned)e[5] << 16);
    o.w = e[6] | ((unsigned)e[7] << 16);
    *(uint4*)(Wt + (size_t)mat * 65536 + (size_t)(tc + n) * 256 + tr + kc) = o;
  }
}

// ---------------- CSR build (both sides per launch) ----------------
__global__ void k_degree2(const int* __restrict__ e1, const int* __restrict__ e2,
                          int* __restrict__ cnt) {
  int b = blockIdx.x;                 // 4096
  int side = b >> 11;
  int e = (b & 2047) * 256 + threadIdx.x;
  const int* dst = (side ? e2 : e1) + NEDGE;
  atomicAdd(&cnt[side * NNODE + dst[e]], 1);
}

__global__ void k_scan2(const int* __restrict__ cnt, int* __restrict__ off,
                        int* __restrict__ cur) {
  __shared__ int sh[1024];
  int side = blockIdx.x;              // grid 2
  const int* c = cnt + side * NNODE;
  int* of = off + side * (NNODE + 64);
  int* cu = cur + side * NNODE;
  int t = threadIdx.x;
  int base = t * 32;
  int loc[32];
  int s = 0;
#pragma unroll
  for (int j = 0; j < 32; j++) { loc[j] = c[base + j]; s += loc[j]; }
  sh[t] = s;
  __syncthreads();
  for (int d = 1; d < 1024; d <<= 1) {
    int v = (t >= d) ? sh[t - d] : 0;
    __syncthreads();
    sh[t] += v;
    __syncthreads();
  }
  int run = sh[t] - s;
#pragma unroll
  for (int j = 0; j < 32; j++) { of[base + j] = run; cu[base + j] = run; run += loc[j]; }
  if (t == 1023) of[NNODE] = run;
}

__global__ void k_scatter2(const int* __restrict__ e1, const int* __restrict__ e2,
                           int* __restrict__ cur, int* __restrict__ srcs) {
  int b = blockIdx.x;                 // 4096
  int side = b >> 11;
  int e = (b & 2047) * 256 + threadIdx.x;
  const int* ei = (side ? e2 : e1);
  int d = ei[NEDGE + e];
  int p = atomicAdd(&cur[side * NNODE + d], 1);
  srcs[side * NEDGE + p] = ei[e];
}

// ---------------- fused layer: gather(+BN) -> GEMM1(relu) -> GEMM2 + stats ----------------
// grid 2048 (2 sides x 1024 row-blocks of 32), 512 thr = 8 waves (2m x 4n), wave tile 16x64.
// LDS 52KB: sA/sA2 [32][512B] at [0,16K), sW [256][128B] at [16K,48K), red 4K at [48K,52K).
// -> 3 blocks/CU (24 waves) for gather concurrency.
template <bool BN>
__global__ __launch_bounds__(512, 6) void k_layer(
    const unsigned short* __restrict__ x,      // [2N][256] prev features
    const int* __restrict__ off, const int* __restrict__ srcs,
    const float* __restrict__ pstats,          // [2][2][256] prev layer (BN only)
    const float* __restrict__ pgamma, const float* __restrict__ pbeta,
    const unsigned short* __restrict__ w1t,    // [256][256] bf16 transposed
    const unsigned short* __restrict__ w2t,
    const float* __restrict__ b1, const float* __restrict__ b2,
    float* __restrict__ stats,                 // [2][2][256] this layer
    unsigned short* __restrict__ hout) {
  __shared__ __align__(16) char smem[53248];
  char* sA = smem;                 // [32][512B] swizzled bf16 (gather out / A operand)
  char* sA2 = smem;                // alias
  char* sW = smem + 16384;         // [256][128B] swizzled W chunk
  float2* red = (float2*)(smem + 49152);   // [256][2]
  int tid = threadIdx.x;
  int lane = tid & 63, wid = tid >> 6;
  int wm = wid & 1, wn = wid >> 1;
  int q = lane >> 4, r = lane & 15;
  const int sw = (r & 7) << 4;
  int b = blockIdx.x;
  int side = b >> 10;
  size_t grow0 = (size_t)side * NNODE + (size_t)(b & 1023) * 32;

  auto stageW = [&](const unsigned short* wsrc, int k0) {
    for (int c = tid; c < 2048; c += 512) {
      int row = c >> 3, cb = (c & 7) * 16;
      float4 v = *(const float4*)(wsrc + (size_t)row * 256 + k0 + (c & 7) * 8);
      *(float4*)(sW + row * 128 + (cb ^ ((row & 7) << 4))) = v;
    }
  };

  stageW(w1t, 0);   // hoisted: loads overlap gather

  // ============ gather phase: aggregate 32 rows into sA ============
  {
    int hw = tid >> 5, sub = tid & 31;       // half-wave owns 2 node rows
    float sc[8], shf[8];
    if (BN) {
      int c0 = sub * 8;
      const float* cs = pstats + side * 512;
      const float invn = 1.f / 32768.f;
#pragma unroll
      for (int j = 0; j < 8; j++) {
        float mu = cs[c0 + j] * invn;
        float var = cs[256 + c0 + j] * invn - mu * mu;
        float s = pgamma[c0 + j] * rsqrtf(var + 1e-5f);
        sc[j] = s; shf[j] = pbeta[c0 + j] - mu * s;
      }
    }
    const uint4* X = (const uint4*)x;        // 32 uint4 per row
    size_t rbase = (size_t)side * NNODE;
    const int* offs = off + side * (NNODE + 64);
    const int* sr = srcs + (size_t)side * NEDGE;
    int nbase = (int)(b & 1023) * 32;

#pragma unroll 1
    for (int nn = 0; nn < 2; nn++) {
      int lrow = hw * 2 + nn;
      int n = nbase + lrow;
      float a[8];
#pragma unroll
      for (int j = 0; j < 8; j++) a[j] = 0.f;
      auto acc8 = [&](uint4 u, float w) {
        unsigned uu[4] = {u.x, u.y, u.z, u.w};
#pragma unroll
        for (int j = 0; j < 4; j++) {
          float lo = __uint_as_float(uu[j] << 16);
          float hi = __uint_as_float(uu[j] & 0xFFFF0000u);
          if (BN) {
            lo = fmaxf(fmaf(lo, sc[2 * j], shf[2 * j]), 0.f);
            hi = fmaxf(fmaf(hi, sc[2 * j + 1], shf[2 * j + 1]), 0.f);
          }
          a[2 * j] = fmaf(lo, w, a[2 * j]);
          a[2 * j + 1] = fmaf(hi, w, a[2 * j + 1]);
        }
      };
      acc8(X[(rbase + n) * 32 + sub], 2.f);
      int e = offs[n], ee = offs[n + 1];
      for (; e + 3 < ee; e += 4) {
        int i0 = sr[e], i1 = sr[e + 1], i2 = sr[e + 2], i3 = sr[e + 3];
        uint4 u0 = X[(rbase + i0) * 32 + sub];
        uint4 u1 = X[(rbase + i1) * 32 + sub];
        uint4 u2 = X[(rbase + i2) * 32 + sub];
        uint4 u3 = X[(rbase + i3) * 32 + sub];
        acc8(u0, 1.f); acc8(u1, 1.f); acc8(u2, 1.f); acc8(u3, 1.f);
      }
      for (; e < ee; e++) acc8(X[(rbase + sr[e]) * 32 + sub], 1.f);
      uint4 o;
      o.x = packbf(a[0], a[1]); o.y = packbf(a[2], a[3]);
      o.z = packbf(a[4], a[5]); o.w = packbf(a[6], a[7]);
      *(uint4*)(sA + lrow * 512 + ((sub * 16) ^ ((lrow & 7) << 4))) = o;
    }
  }

  f32x4 acc[4];
#pragma unroll
  for (int ni = 0; ni < 4; ni++) acc[ni] = (f32x4){0.f, 0.f, 0.f, 0.f};

  __syncthreads();

  // ---- phase 1: C1 = A @ W1 ----
  for (int k0 = 0; k0 < 256; k0 += 64) {
#pragma unroll
    for (int ks = 0; ks < 2; ks++) {
      bf16x8 af, bfr[4];
      int cbA = (k0 * 2 + ks * 64 + q * 16) ^ sw;
      int cbW = (ks * 64 + q * 16) ^ sw;
      af = *(const bf16x8*)(sA + (wm * 16 + r) * 512 + cbA);
#pragma unroll
      for (int ni = 0; ni < 4; ni++)
        bfr[ni] = *(const bf16x8*)(sW + (wn * 64 + ni * 16 + r) * 128 + cbW);
#pragma unroll
      for (int ni = 0; ni < 4; ni++)
        acc[ni] = __builtin_amdgcn_mfma_f32_16x16x32_bf16(af, bfr[ni], acc[ni], 0, 0, 0);
    }
    __syncthreads();
    if (k0 < 192) {
      stageW(w1t, k0 + 64);
      __syncthreads();
    }
  }

  // epilogue 1: bias + relu -> bf16 into sA2 (alias of sA; all reads done)
  float b1v[4];
#pragma unroll
  for (int ni = 0; ni < 4; ni++) b1v[ni] = b1[wn * 64 + ni * 16 + r];
#pragma unroll
  for (int ni = 0; ni < 4; ni++)
#pragma unroll
    for (int j = 0; j < 4; j++) {
      float o = fmaxf(acc[ni][j] + b1v[ni], 0.f);
      int rowc = wm * 16 + q * 4 + j;
      int colc = wn * 64 + ni * 16 + r;
      *(unsigned short*)(sA2 + rowc * 512 + ((colc * 2) ^ (((q * 4 + j) & 7) << 4))) = f2bf(o);
    }
#pragma unroll
  for (int ni = 0; ni < 4; ni++) acc[ni] = (f32x4){0.f, 0.f, 0.f, 0.f};
  stageW(w2t, 0);
  __syncthreads();

  // ---- phase 2: C2 = relu(C1) @ W2 ----
  for (int k0 = 0; k0 < 256; k0 += 64) {
#pragma unroll
    for (int ks = 0; ks < 2; ks++) {
      bf16x8 af, bfr[4];
      int cbA = (k0 * 2 + ks * 64 + q * 16) ^ sw;
      int cbW = (ks * 64 + q * 16) ^ sw;
      af = *(const bf16x8*)(sA2 + (wm * 16 + r) * 512 + cbA);
#pragma unroll
      for (int ni = 0; ni < 4; ni++)
        bfr[ni] = *(const bf16x8*)(sW + (wn * 64 + ni * 16 + r) * 128 + cbW);
#pragma unroll
      for (int ni = 0; ni < 4; ni++)
        acc[ni] = __builtin_amdgcn_mfma_f32_16x16x32_bf16(af, bfr[ni], acc[ni], 0, 0, 0);
    }
    __syncthreads();
    if (k0 < 192) {
      stageW(w2t, k0 + 64);
      __syncthreads();
    }
  }

  // epilogue 2: bias, BN stats (shfl + LDS cross-wave reduce + atomics), bf16 out
  float b2v[4];
#pragma unroll
  for (int ni = 0; ni < 4; ni++) b2v[ni] = b2[wn * 64 + ni * 16 + r];
#pragma unroll
  for (int ni = 0; ni < 4; ni++) {
    float ss = 0.f, sq = 0.f;
#pragma unroll
    for (int j = 0; j < 4; j++) {
      float o = acc[ni][j] + b2v[ni];
      acc[ni][j] = o;
      ss += o; sq += o * o;
    }
    ss += __shfl_xor(ss, 16, 64); ss += __shfl_xor(ss, 32, 64);
    sq += __shfl_xor(sq, 16, 64); sq += __shfl_xor(sq, 32, 64);
    if (q == 0) {
      float2 w; w.x = ss; w.y = sq;
      red[(wn * 64 + ni * 16 + r) * 2 + wm] = w;
    }
  }
  __syncthreads();
  float* cs = stats + side * 512;
  if (tid < 256) {
    float2 a = red[tid * 2], c2 = red[tid * 2 + 1];
    atomicAdd(&cs[tid], a.x + c2.x);
    atomicAdd(&cs[256 + tid], a.y + c2.y);
  }
  // bf16 out via sA2 bounce (phase-2 reads done; note: overwrites sA2 after sync)
#pragma unroll
  for (int ni = 0; ni < 4; ni++)
#pragma unroll
    for (int j = 0; j < 4; j++) {
      int rowc = wm * 16 + q * 4 + j;
      int colc = wn * 64 + ni * 16 + r;
      *(unsigned short*)(sA2 + rowc * 512 + ((colc * 2) ^ (((q * 4 + j) & 7) << 4))) =
          f2bf(acc[ni][j]);
    }
  __syncthreads();
  for (int c = tid; c < 1024; c += 512) {   // 32 rows x 32 chunks of 16B
    int row = c >> 5, cb = (c & 31) * 16;
    float4 v = *(const float4*)(sA2 + row * 512 + (cb ^ ((row & 7) << 4)));
    *(float4*)(hout + (grow0 + row) * 256 + (c & 31) * 8) = v;
  }
}

// ---------------- per-graph sum of relu(bn(h)) ----------------
__global__ __launch_bounds__(256) void k_gsum(
    const unsigned short* __restrict__ h, const float* __restrict__ stats,
    const float* __restrict__ gamma, const float* __restrict__ beta,
    float* __restrict__ sg) {
  int b = blockIdx.x;            // 256 = 2 sides x 128 graphs
  int side = b >> 7, g = b & 127;
  int t = threadIdx.x;
  int c0 = (t & 63) * 4, rg = t >> 6;
  const float* cs = stats + side * 512;
  float sc[4], sh_[4];
#pragma unroll
  for (int j = 0; j < 4; j++) {
    float mu = cs[c0 + j] * (1.f / 32768.f);
    float var = cs[256 + c0 + j] * (1.f / 32768.f) - mu * mu;
    float s = gamma[c0 + j] * rsqrtf(var + 1e-5f);
    sc[j] = s; sh_[j] = beta[c0 + j] - mu * s;
  }
  size_t base = (size_t)side * NNODE + (size_t)g * 256;
  float acc = 0.f;
  for (int k = 0; k < 64; k++) {
    int row = rg + k * 4;
    ushort4 u = *(const ushort4*)(h + (base + row) * 256 + c0);
    acc += fmaxf(fmaf(bf2f(u.x), sc[0], sh_[0]), 0.f);
    acc += fmaxf(fmaf(bf2f(u.y), sc[1], sh_[1]), 0.f);
    acc += fmaxf(fmaf(bf2f(u.z), sc[2], sh_[2]), 0.f);
    acc += fmaxf(fmaf(bf2f(u.w), sc[3], sh_[3]), 0.f);
  }
  __shared__ float red[256];
  red[t] = acc;
  __syncthreads();
  if (t < 64) {
    float s = red[t] + red[t + 64] + red[t + 128] + red[t + 192];
#pragma unroll
    for (int m = 1; m < 64; m <<= 1) s += __shfl_xor(s, m, 64);
    if (t == 0) sg[b] = s;
  }
}

// ---------------- final: p = sg1 - sg2, min-max normalize, exp(-p) ----------------
__global__ void k_final(const float* __restrict__ sg1, const float* __restrict__ sg2,
                        float* __restrict__ out) {
  int t = threadIdx.x;   // 64 threads
  float a = sg1[t] - sg2[t];
  float b = sg1[t + 64] - sg2[t + 64];
  float mn = fminf(a, b), mx = fmaxf(a, b);
#pragma unroll
  for (int msk = 1; msk < 64; msk <<= 1) {
    mn = fminf(mn, __shfl_xor(mn, msk, 64));
    mx = fmaxf(mx, __shfl_xor(mx, msk, 64));
  }
  float inv = 1.0f / (mx - mn);
  out[t] = __expf(-(a - mn) * inv);
  out[t + 64] = __expf(-(b - mn) * inv);
}

// ---------------- host ----------------
extern "C" void kernel_launch(void* const* d_in, const int* in_sizes, int n_in,
                              void* d_out, int out_size, void* d_ws, size_t ws_size,
                              hipStream_t stream) {
  (void)in_sizes; (void)n_in; (void)out_size; (void)ws_size;
  const float* f1 = (const float*)d_in[0];
  const float* f2 = (const float*)d_in[1];
  const int* e1 = (const int*)d_in[2];
  const int* e2 = (const int*)d_in[3];
  const float* gw1 = (const float*)d_in[5];
  const float* gb1 = (const float*)d_in[6];
  const float* gw2 = (const float*)d_in[7];
  const float* gb2 = (const float*)d_in[8];
  const float* gga = (const float*)d_in[9];
  const float* gbe = (const float*)d_in[10];
  float* out = (float*)d_out;

  char* ws = (char*)d_ws;
  size_t o = 0;
  auto alloc = [&](size_t bytes) { void* p = ws + o; o += (bytes + 255) & ~(size_t)255; return p; };
  unsigned short* hb0 = (unsigned short*)alloc(2ull * NNODE * 256 * 2);
  unsigned short* hb1 = (unsigned short*)alloc(2ull * NNODE * 256 * 2);
  unsigned short* Wt = (unsigned short*)alloc(6ull * 65536 * 2);
  float* stats = (float*)alloc(3 * 1024 * 4);      // [layer][side][{sum,sq}][256]
  float* sg = (float*)alloc(256 * 4);
  int* cnt = (int*)alloc(2 * NNODE * 4);
  int* off = (int*)alloc(2 * (NNODE + 64) * 4);
  int* cur = (int*)alloc(2 * NNODE * 4);
  int* srcs = (int*)alloc(2ull * NEDGE * 4);

  (void)hipMemsetAsync(stats, 0, 3 * 1024 * 4, stream);
  (void)hipMemsetAsync(cnt, 0, 2 * NNODE * 4, stream);

  k_conv<<<16384, 256, 0, stream>>>(f1, f2, hb0);
  k_wprep<<<96, 256, 0, stream>>>(gw1, gw2, Wt);
  k_degree2<<<4096, 256, 0, stream>>>(e1, e2, cnt);
  k_scan2<<<2, 1024, 0, stream>>>(cnt, off, cur);
  k_scatter2<<<4096, 256, 0, stream>>>(e1, e2, cur, srcs);

  unsigned short* hb[2] = {hb0, hb1};
  for (int l = 0; l < 3; l++) {
    unsigned short* xin = hb[l & 1];
    unsigned short* hout = hb[1 - (l & 1)];
    if (l == 0)
      k_layer<false><<<2048, 512, 0, stream>>>(
          xin, off, srcs, nullptr, nullptr, nullptr,
          Wt + (size_t)l * 65536, Wt + (size_t)(3 + l) * 65536,
          gb1 + l * 256, gb2 + l * 256, stats + l * 1024, hout);
    else
      k_layer<true><<<2048, 512, 0, stream>>>(
          xin, off, srcs, stats + (l - 1) * 1024, gga + (l - 1) * 256, gbe + (l - 1) * 256,
          Wt + (size_t)l * 65536, Wt + (size_t)(3 + l) * 65536,
          gb1 + l * 256, gb2 + l * 256, stats + l * 1024, hout);
  }

  k_gsum<<<256, 256, 0, stream>>>(hb1, stats + 2 * 1024, gga + 512, gbe + 512, sg);
  k_final<<<1, 64, 0, stream>>>(sg, sg + 128, out);
}

// Round 10
// 487.972 us; speedup vs baseline: 1.1724x; 1.1390x over previous
//
#include <hip/hip_runtime.h>

// GSModel pipeline, round 10.
//  - p_b = sum(g1_b) - sum(g2_b) identity (sinkhorn colsum==1) — scores path removed.
//  - bf16 storage; MFMA 16x16x32 bf16, XOR-swizzled LDS; fused gather+GEMM1+GEMM2.
//  - Gather is at the per-CU load-throughput ceiling (~72us/layer floor) — rounds
//    5/8/9 proved residency tricks and occupancy don't help. This round amortizes
//    the NON-gather cost: 128-row tiles (grid 512, 2 blocks/CU, 80KB LDS) halve
//    W re-staging traffic and barrier-rounds per row. Wt pre-chunked [k0/32][n][k32]
//    so 16KB W stages are linear/coalesced.
//  - Prep: conv+wprep+degree fused into k_prep; scan rewritten shfl-based.

constexpr int NNODE = 32768;
constexpr int NEDGE = 524288;

typedef __attribute__((ext_vector_type(8))) short bf16x8;
typedef __attribute__((ext_vector_type(4))) float f32x4;

__device__ __forceinline__ float bf2f(unsigned short u) {
  return __uint_as_float((unsigned)u << 16);
}
__device__ __forceinline__ unsigned short f2bf(float f) {
  unsigned u = __float_as_uint(f);
  return (unsigned short)((u + 0x7FFFu + ((u >> 16) & 1u)) >> 16);
}
__device__ __forceinline__ unsigned packbf(float a, float b) {
  return (unsigned)f2bf(a) | ((unsigned)f2bf(b) << 16);
}

// ---------------- fused prep: conv (16384) | wprep (96) | degree (4096) ----------------
__global__ __launch_bounds__(256) void k_prep(
    const float* __restrict__ f1, const float* __restrict__ f2,
    unsigned short* __restrict__ hb0,
    const float* __restrict__ gw1, const float* __restrict__ gw2,
    unsigned short* __restrict__ Wt,
    const int* __restrict__ e1, const int* __restrict__ e2,
    int* __restrict__ cnt) {
  __shared__ float sh[64][65];
  int b = blockIdx.x, t = threadIdx.x;
  if (b < 16384) {
    // f32 -> bf16 feature convert
    size_t i = (size_t)b * 256 + t;     // 4,194,304 chunks of 4
    const float* src = (i < 2097152) ? (f1 + i * 4) : (f2 + (i - 2097152) * 4);
    float4 v = *(const float4*)src;
    ushort4 o;
    o.x = f2bf(v.x); o.y = f2bf(v.y); o.z = f2bf(v.z); o.w = f2bf(v.w);
    *(ushort4*)(hb0 + i * 4) = o;
  } else if (b < 16480) {
    // weight transpose + convert + k-chunked layout: Wt[mat][k0/32][n][k%32]
    int bb = b - 16384;                 // 96 = 6 mats x 16 tiles of 64x64
    int mat = bb >> 4, tile = bb & 15;
    int tr = (tile >> 2) * 64, tc = (tile & 3) * 64;   // tr = k-range, tc = n-range
    const float* src = (mat < 3) ? (gw1 + (size_t)mat * 65536) : (gw2 + (size_t)(mat - 3) * 65536);
#pragma unroll
    for (int i = 0; i < 4; i++) {
      int c = t + i * 256;              // 1024 float4 chunks
      int row = c >> 4, c4 = (c & 15) * 4;
      float4 v = *(const float4*)(src + (size_t)(tr + row) * 256 + tc + c4);
      sh[row][c4] = v.x; sh[row][c4 + 1] = v.y; sh[row][c4 + 2] = v.z; sh[row][c4 + 3] = v.w;
    }
    __syncthreads();
#pragma unroll
    for (int i = 0; i < 2; i++) {
      int c = t + i * 256;              // 512 chunks of 8 bf16
      int n = c >> 3, kc = (c & 7) * 8; // n local, k local (within 64x64 tile)
      unsigned short e[8];
#pragma unroll
      for (int j = 0; j < 8; j++) e[j] = f2bf(sh[kc + j][n]);
      uint4 o;
      o.x = e[0] | ((unsigned)e[1] << 16);
      o.y = e[2] | ((unsigned)e[3] << 16);
      o.z = e[4] | ((unsigned)e[5] << 16);
      o.w = e[6] | ((unsigned)e[7] << 16);
      int kg = tr + kc;                 // global k, 8-aligned
      size_t idx = (size_t)mat * 65536 + (size_t)(kg >> 5) * 8192 + (size_t)(tc + n) * 32 + (kg & 31);
      *(uint4*)(Wt + idx) = o;
    }
  } else {
    // degree count
    int bb = b - 16480;                 // 4096
    int side = bb >> 11;
    int e = (bb & 2047) * 256 + t;
    const int* dst = (side ? e2 : e1) + NEDGE;
    atomicAdd(&cnt[side * NNODE + dst[e]], 1);
  }
}

// ---------------- scan: shfl-based, 3 barriers ----------------
__global__ __launch_bounds__(1024) void k_scan2(const int* __restrict__ cnt,
                                                int* __restrict__ off,
                                                int* __restrict__ cur) {
  int side = blockIdx.x;                // grid 2
  const int* c = cnt + side * NNODE;
  int* of = off + side * (NNODE + 64);
  int* cu = cur + side * NNODE;
  int t = threadIdx.x;                  // 1024
  int lane = t & 63, wv = t >> 6;
  int base = t * 32;
  int loc[32];
  int s = 0;
#pragma unroll
  for (int j = 0; j < 32; j++) { loc[j] = c[base + j]; s += loc[j]; }
  int tot = s;
  // inclusive wave scan
#pragma unroll
  for (int d = 1; d < 64; d <<= 1) {
    int v = __shfl_up(s, d, 64);
    if (lane >= d) s += v;
  }
  __shared__ int ws[16];
  if (lane == 63) ws[wv] = s;
  __syncthreads();
  if (t < 16) {
    int w = ws[t];
#pragma unroll
    for (int d = 1; d < 16; d <<= 1) {
      int v = __shfl_up(w, d, 64);
      if (t >= d) w += v;
    }
    ws[t] = w;                          // inclusive wave-prefix
  }
  __syncthreads();
  int run = s - tot + (wv ? ws[wv - 1] : 0);   // exclusive prefix for this thread
#pragma unroll
  for (int j = 0; j < 32; j++) { of[base + j] = run; cu[base + j] = run; run += loc[j]; }
  if (t == 1023) of[NNODE] = run;
}

__global__ void k_scatter2(const int* __restrict__ e1, const int* __restrict__ e2,
                           int* __restrict__ cur, int* __restrict__ srcs) {
  int b = blockIdx.x;                   // 4096
  int side = b >> 11;
  int e = (b & 2047) * 256 + threadIdx.x;
  const int* ei = (side ? e2 : e1);
  int d = ei[NEDGE + e];
  int p = atomicAdd(&cur[side * NNODE + d], 1);
  srcs[side * NEDGE + p] = ei[e];
}

// ---------------- fused layer: gather(+BN) -> GEMM1(relu) -> GEMM2 + stats ----------------
// grid 512 (2 sides x 256 row-blocks of 128), 512 thr = 8 waves (2m x 4n), wave tile 64x64.
// LDS 80KB: sA/sA2 [128][512B] at [0,64K), sW [256][64B] (k-chunk 32) at [64K,80K);
// red (4KB) aliases sW after phase 2. -> 2 blocks/CU.
template <bool BN>
__global__ __launch_bounds__(512, 4) void k_layer(
    const unsigned short* __restrict__ x,      // [2N][256] prev features
    const int* __restrict__ off, const int* __restrict__ srcs,
    const float* __restrict__ pstats,          // [2][2][256] prev layer (BN only)
    const float* __restrict__ pgamma, const float* __restrict__ pbeta,
    const unsigned short* __restrict__ w1t,    // chunked [8][256][32] bf16
    const unsigned short* __restrict__ w2t,
    const float* __restrict__ b1, const float* __restrict__ b2,
    float* __restrict__ stats,                 // [2][2][256] this layer
    unsigned short* __restrict__ hout) {
  __shared__ __align__(16) char smem[81920];
  char* sA = smem;                 // [128][512B] swizzled bf16
  char* sA2 = smem;                // alias
  char* sW = smem + 65536;         // [256][64B] swizzled W k-chunk
  float2* red = (float2*)(smem + 65536);   // alias of sW, used after phase 2
  int tid = threadIdx.x;
  int lane = tid & 63, wid = tid >> 6;
  int wm = wid & 1, wn = wid >> 1;
  int q = lane >> 4, r = lane & 15;
  const int swA = (r & 7) << 4;
  const int swW = ((r >> 1) & 3) << 4;
  int b = blockIdx.x;
  int side = b >> 8;
  size_t grow0 = (size_t)side * NNODE + (size_t)(b & 255) * 128;

  auto stageW = [&](const unsigned short* wsrc, int k0) {
    const unsigned short* basep = wsrc + (size_t)(k0 >> 5) * 8192;   // 16KB linear chunk
#pragma unroll
    for (int it = 0; it < 2; it++) {
      int c = tid + it * 512;            // 1024 float4 chunks
      int row = c >> 2, ch = c & 3;
      float4 v = *(const float4*)(basep + (size_t)c * 8);
      *(float4*)(sW + row * 64 + ((ch * 16) ^ (((row >> 1) & 3) << 4))) = v;
    }
  };

  stageW(w1t, 0);   // hoisted: loads overlap gather

  // ============ gather phase: aggregate 128 rows into sA ============
  {
    int hw = tid >> 5, sub = tid & 31;   // half-wave owns 8 node rows
    float sc[8], shf[8];
    if (BN) {
      int c0 = sub * 8;
      const float* cs = pstats + side * 512;
      const float invn = 1.f / 32768.f;
#pragma unroll
      for (int j = 0; j < 8; j++) {
        float mu = cs[c0 + j] * invn;
        float var = cs[256 + c0 + j] * invn - mu * mu;
        float s = pgamma[c0 + j] * rsqrtf(var + 1e-5f);
        sc[j] = s; shf[j] = pbeta[c0 + j] - mu * s;
      }
    }
    const uint4* X = (const uint4*)x;    // 32 uint4 per row
    size_t rbase = (size_t)side * NNODE;
    const int* offs = off + side * (NNODE + 64);
    const int* sr = srcs + (size_t)side * NEDGE;
    int nbase = (int)(b & 255) * 128;

#pragma unroll 1
    for (int nn = 0; nn < 8; nn++) {
      int lrow = hw * 8 + nn;
      int n = nbase + lrow;
      float a[8];
#pragma unroll
      for (int j = 0; j < 8; j++) a[j] = 0.f;
      auto acc8 = [&](uint4 u, float w) {
        unsigned uu[4] = {u.x, u.y, u.z, u.w};
#pragma unroll
        for (int j = 0; j < 4; j++) {
          float lo = __uint_as_float(uu[j] << 16);
          float hi = __uint_as_float(uu[j] & 0xFFFF0000u);
          if (BN) {
            lo = fmaxf(fmaf(lo, sc[2 * j], shf[2 * j]), 0.f);
            hi = fmaxf(fmaf(hi, sc[2 * j + 1], shf[2 * j + 1]), 0.f);
          }
          a[2 * j] = fmaf(lo, w, a[2 * j]);
          a[2 * j + 1] = fmaf(hi, w, a[2 * j + 1]);
        }
      };
      acc8(X[(rbase + n) * 32 + sub], 2.f);
      int e = offs[n], ee = offs[n + 1];
      for (; e + 3 < ee; e += 4) {
        int i0 = sr[e], i1 = sr[e + 1], i2 = sr[e + 2], i3 = sr[e + 3];
        uint4 u0 = X[(rbase + i0) * 32 + sub];
        uint4 u1 = X[(rbase + i1) * 32 + sub];
        uint4 u2 = X[(rbase + i2) * 32 + sub];
        uint4 u3 = X[(rbase + i3) * 32 + sub];
        acc8(u0, 1.f); acc8(u1, 1.f); acc8(u2, 1.f); acc8(u3, 1.f);
      }
      for (; e < ee; e++) acc8(X[(rbase + sr[e]) * 32 + sub], 1.f);
      uint4 o;
      o.x = packbf(a[0], a[1]); o.y = packbf(a[2], a[3]);
      o.z = packbf(a[4], a[5]); o.w = packbf(a[6], a[7]);
      *(uint4*)(sA + lrow * 512 + ((sub * 16) ^ ((lrow & 7) << 4))) = o;
    }
  }

  f32x4 acc[4][4];
#pragma unroll
  for (int mi = 0; mi < 4; mi++)
#pragma unroll
    for (int ni = 0; ni < 4; ni++) acc[mi][ni] = (f32x4){0.f, 0.f, 0.f, 0.f};

  __syncthreads();

  // ---- phase 1: C1 = A @ W1 ----
  for (int k0 = 0; k0 < 256; k0 += 32) {
    bf16x8 af[4], bfr[4];
    int cbA = (k0 * 2 + q * 16) ^ swA;
    int cbW = (q * 16) ^ swW;
#pragma unroll
    for (int mi = 0; mi < 4; mi++)
      af[mi] = *(const bf16x8*)(sA + (wm * 64 + mi * 16 + r) * 512 + cbA);
#pragma unroll
    for (int ni = 0; ni < 4; ni++)
      bfr[ni] = *(const bf16x8*)(sW + (wn * 64 + ni * 16 + r) * 64 + cbW);
#pragma unroll
    for (int mi = 0; mi < 4; mi++)
#pragma unroll
      for (int ni = 0; ni < 4; ni++)
        acc[mi][ni] = __builtin_amdgcn_mfma_f32_16x16x32_bf16(af[mi], bfr[ni], acc[mi][ni], 0, 0, 0);
    __syncthreads();
    if (k0 < 224) {
      stageW(w1t, k0 + 32);
      __syncthreads();
    }
  }

  // epilogue 1: bias + relu -> bf16 into sA2 (alias of sA; all reads done)
  float b1v[4];
#pragma unroll
  for (int ni = 0; ni < 4; ni++) b1v[ni] = b1[wn * 64 + ni * 16 + r];
#pragma unroll
  for (int mi = 0; mi < 4; mi++)
#pragma unroll
    for (int ni = 0; ni < 4; ni++)
#pragma unroll
      for (int j = 0; j < 4; j++) {
        float o = fmaxf(acc[mi][ni][j] + b1v[ni], 0.f);
        int rowc = wm * 64 + mi * 16 + q * 4 + j;
        int colc = wn * 64 + ni * 16 + r;
        *(unsigned short*)(sA2 + rowc * 512 + ((colc * 2) ^ (((q * 4 + j) & 7) << 4))) = f2bf(o);
      }
#pragma unroll
  for (int mi = 0; mi < 4; mi++)
#pragma unroll
    for (int ni = 0; ni < 4; ni++) acc[mi][ni] = (f32x4){0.f, 0.f, 0.f, 0.f};
  stageW(w2t, 0);
  __syncthreads();

  // ---- phase 2: C2 = relu(C1) @ W2 ----
  for (int k0 = 0; k0 < 256; k0 += 32) {
    bf16x8 af[4], bfr[4];
    int cbA = (k0 * 2 + q * 16) ^ swA;
    int cbW = (q * 16) ^ swW;
#pragma unroll
    for (int mi = 0; mi < 4; mi++)
      af[mi] = *(const bf16x8*)(sA2 + (wm * 64 + mi * 16 + r) * 512 + cbA);
#pragma unroll
    for (int ni = 0; ni < 4; ni++)
      bfr[ni] = *(const bf16x8*)(sW + (wn * 64 + ni * 16 + r) * 64 + cbW);
#pragma unroll
    for (int mi = 0; mi < 4; mi++)
#pragma unroll
      for (int ni = 0; ni < 4; ni++)
        acc[mi][ni] = __builtin_amdgcn_mfma_f32_16x16x32_bf16(af[mi], bfr[ni], acc[mi][ni], 0, 0, 0);
    __syncthreads();
    if (k0 < 224) {
      stageW(w2t, k0 + 32);
      __syncthreads();
    }
  }

  // epilogue 2: bias, BN stats (shfl + red in sW region + atomics), bf16 out via sA2
  float b2v[4];
#pragma unroll
  for (int ni = 0; ni < 4; ni++) b2v[ni] = b2[wn * 64 + ni * 16 + r];
#pragma unroll
  for (int ni = 0; ni < 4; ni++) {
    float ss = 0.f, sq = 0.f;
#pragma unroll
    for (int mi = 0; mi < 4; mi++)
#pragma unroll
      for (int j = 0; j < 4; j++) {
        float o = acc[mi][ni][j] + b2v[ni];
        acc[mi][ni][j] = o;
        ss += o; sq += o * o;
      }
    ss += __shfl_xor(ss, 16, 64); ss += __shfl_xor(ss, 32, 64);
    sq += __shfl_xor(sq, 16, 64); sq += __shfl_xor(sq, 32, 64);
    if (q == 0) {
      float2 w; w.x = ss; w.y = sq;
      red[(wn * 64 + ni * 16 + r) * 2 + wm] = w;   // sW dead after phase 2 (last sync above)
    }
  }
#pragma unroll
  for (int mi = 0; mi < 4; mi++)
#pragma unroll
    for (int ni = 0; ni < 4; ni++)
#pragma unroll
      for (int j = 0; j < 4; j++) {
        int rowc = wm * 64 + mi * 16 + q * 4 + j;
        int colc = wn * 64 + ni * 16 + r;
        *(unsigned short*)(sA2 + rowc * 512 + ((colc * 2) ^ (((q * 4 + j) & 7) << 4))) =
            f2bf(acc[mi][ni][j]);
      }
  __syncthreads();
  float* cs = stats + side * 512;
  if (tid < 256) {
    float2 a = red[tid * 2], c2 = red[tid * 2 + 1];
    atomicAdd(&cs[tid], a.x + c2.x);
    atomicAdd(&cs[256 + tid], a.y + c2.y);
  }
  for (int c = tid; c < 4096; c += 512) {   // 128 rows x 32 chunks of 16B
    int row = c >> 5, cb = (c & 31) * 16;
    float4 v = *(const float4*)(sA2 + row * 512 + (cb ^ ((row & 7) << 4)));
    *(float4*)(hout + (grow0 + row) * 256 + (c & 31) * 8) = v;
  }
}

// ---------------- per-graph sum of relu(bn(h)) ----------------
__global__ __launch_bounds__(256) void k_gsum(
    const unsigned short* __restrict__ h, const float* __restrict__ stats,
    const float* __restrict__ gamma, const float* __restrict__ beta,
    float* __restrict__ sg) {
  int b = blockIdx.x;            // 256 = 2 sides x 128 graphs
  int side = b >> 7, g = b & 127;
  int t = threadIdx.x;
  int c0 = (t & 63) * 4, rg = t >> 6;
  const float* cs = stats + side * 512;
  float sc[4], sh_[4];
#pragma unroll
  for (int j = 0; j < 4; j++) {
    float mu = cs[c0 + j] * (1.f / 32768.f);
    float var = cs[256 + c0 + j] * (1.f / 32768.f) - mu * mu;
    float s = gamma[c0 + j] * rsqrtf(var + 1e-5f);
    sc[j] = s; sh_[j] = beta[c0 + j] - mu * s;
  }
  size_t base = (size_t)side * NNODE + (size_t)g * 256;
  float acc = 0.f;
  for (int k = 0; k < 64; k++) {
    int row = rg + k * 4;
    ushort4 u = *(const ushort4*)(h + (base + row) * 256 + c0);
    acc += fmaxf(fmaf(bf2f(u.x), sc[0], sh_[0]), 0.f);
    acc += fmaxf(fmaf(bf2f(u.y), sc[1], sh_[1]), 0.f);
    acc += fmaxf(fmaf(bf2f(u.z), sc[2], sh_[2]), 0.f);
    acc += fmaxf(fmaf(bf2f(u.w), sc[3], sh_[3]), 0.f);
  }
  __shared__ float red[256];
  red[t] = acc;
  __syncthreads();
  if (t < 64) {
    float s = red[t] + red[t + 64] + red[t + 128] + red[t + 192];
#pragma unroll
    for (int m = 1; m < 64; m <<= 1) s += __shfl_xor(s, m, 64);
    if (t == 0) sg[b] = s;
  }
}

// ---------------- final: p = sg1 - sg2, min-max normalize, exp(-p) ----------------
__global__ void k_final(const float* __restrict__ sg1, const float* __restrict__ sg2,
                        float* __restrict__ out) {
  int t = threadIdx.x;   // 64 threads
  float a = sg1[t] - sg2[t];
  float b = sg1[t + 64] - sg2[t + 64];
  float mn = fminf(a, b), mx = fmaxf(a, b);
#pragma unroll
  for (int msk = 1; msk < 64; msk <<= 1) {
    mn = fminf(mn, __shfl_xor(mn, msk, 64));
    mx = fmaxf(mx, __shfl_xor(mx, msk, 64));
  }
  float inv = 1.0f / (mx - mn);
  out[t] = __expf(-(a - mn) * inv);
  out[t + 64] = __expf(-(b - mn) * inv);
}

// ---------------- host ----------------
extern "C" void kernel_launch(void* const* d_in, const int* in_sizes, int n_in,
                              void* d_out, int out_size, void* d_ws, size_t ws_size,
                              hipStream_t stream) {
  (void)in_sizes; (void)n_in; (void)out_size; (void)ws_size;
  const float* f1 = (const float*)d_in[0];
  const float* f2 = (const float*)d_in[1];
  const int* e1 = (const int*)d_in[2];
  const int* e2 = (const int*)d_in[3];
  const float* gw1 = (const float*)d_in[5];
  const float* gb1 = (const float*)d_in[6];
  const float* gw2 = (const float*)d_in[7];
  const float* gb2 = (const float*)d_in[8];
  const float* gga = (const float*)d_in[9];
  const float* gbe = (const float*)d_in[10];
  float* out = (float*)d_out;

  char* ws = (char*)d_ws;
  size_t o = 0;
  auto alloc = [&](size_t bytes) { void* p = ws + o; o += (bytes + 255) & ~(size_t)255; return p; };
  unsigned short* hb0 = (unsigned short*)alloc(2ull * NNODE * 256 * 2);
  unsigned short* hb1 = (unsigned short*)alloc(2ull * NNODE * 256 * 2);
  unsigned short* Wt = (unsigned short*)alloc(6ull * 65536 * 2);
  float* stats = (float*)alloc(3 * 1024 * 4);      // [layer][side][{sum,sq}][256]
  float* sg = (float*)alloc(256 * 4);
  int* cnt = (int*)alloc(2 * NNODE * 4);
  int* off = (int*)alloc(2 * (NNODE + 64) * 4);
  int* cur = (int*)alloc(2 * NNODE * 4);
  int* srcs = (int*)alloc(2ull * NEDGE * 4);

  (void)hipMemsetAsync(stats, 0, 3 * 1024 * 4, stream);
  (void)hipMemsetAsync(cnt, 0, 2 * NNODE * 4, stream);

  k_prep<<<20576, 256, 0, stream>>>(f1, f2, hb0, gw1, gw2, Wt, e1, e2, cnt);
  k_scan2<<<2, 1024, 0, stream>>>(cnt, off, cur);
  k_scatter2<<<4096, 256, 0, stream>>>(e1, e2, cur, srcs);

  unsigned short* hb[2] = {hb0, hb1};
  for (int l = 0; l < 3; l++) {
    unsigned short* xin = hb[l & 1];
    unsigned short* hout = hb[1 - (l & 1)];
    if (l == 0)
      k_layer<false><<<512, 512, 0, stream>>>(
          xin, off, srcs, nullptr, nullptr, nullptr,
          Wt + (size_t)l * 65536, Wt + (size_t)(3 + l) * 65536,
          gb1 + l * 256, gb2 + l * 256, stats + l * 1024, hout);
    else
      k_layer<true><<<512, 512, 0, stream>>>(
          xin, off, srcs, stats + (l - 1) * 1024, gga + (l - 1) * 256, gbe + (l - 1) * 256,
          Wt + (size_t)l * 65536, Wt + (size_t)(3 + l) * 65536,
          gb1 + l * 256, gb2 + l * 256, stats + l * 1024, hout);
  }

  k_gsum<<<256, 256, 0, stream>>>(hb1, stats + 2 * 1024, gga + 512, gbe + 512, sg);
  k_final<<<1, 64, 0, stream>>>(sg, sg + 128, out);
}

// Round 11
// 429.336 us; speedup vs baseline: 1.3325x; 1.1366x over previous
//
#include <hip/hip_runtime.h>

// GSModel pipeline, round 11.
//  - p_b = sum(g1_b) - sum(g2_b) identity (sinkhorn colsum==1) — scores path removed.
//  - bf16 storage; MFMA 16x16x32 bf16, XOR-swizzled LDS; fused gather+GEMM1+GEMM2
//    k_layer UNCHANGED from round 10 except CSR indexing (validated gather-latency floor).
//  - NEW: one-pass CSR build with fixed-capacity slots: srcs64[node][64] ushort,
//    slot = atomicAdd(cnt[dst]). Degrees ~Poisson(16): P(deg>=64) ~ 1e-19/node.
//    Deletes degree pass + k_scan2 + k_scatter2 (3 passes -> 1). ushort ids halve
//    index traffic.

constexpr int NNODE = 32768;
constexpr int NEDGE = 524288;

typedef __attribute__((ext_vector_type(8))) short bf16x8;
typedef __attribute__((ext_vector_type(4))) float f32x4;

__device__ __forceinline__ float bf2f(unsigned short u) {
  return __uint_as_float((unsigned)u << 16);
}
__device__ __forceinline__ unsigned short f2bf(float f) {
  unsigned u = __float_as_uint(f);
  return (unsigned short)((u + 0x7FFFu + ((u >> 16) & 1u)) >> 16);
}
__device__ __forceinline__ unsigned packbf(float a, float b) {
  return (unsigned)f2bf(a) | ((unsigned)f2bf(b) << 16);
}

// ---------------- fused prep: conv (16384) | wprep (96) | CSR build (4096) ----------------
__global__ __launch_bounds__(256) void k_prep(
    const float* __restrict__ f1, const float* __restrict__ f2,
    unsigned short* __restrict__ hb0,
    const float* __restrict__ gw1, const float* __restrict__ gw2,
    unsigned short* __restrict__ Wt,
    const int* __restrict__ e1, const int* __restrict__ e2,
    int* __restrict__ cnt, unsigned short* __restrict__ srcs64) {
  __shared__ float sh[64][65];
  int b = blockIdx.x, t = threadIdx.x;
  if (b < 16384) {
    // f32 -> bf16 feature convert
    size_t i = (size_t)b * 256 + t;     // 4,194,304 chunks of 4
    const float* src = (i < 2097152) ? (f1 + i * 4) : (f2 + (i - 2097152) * 4);
    float4 v = *(const float4*)src;
    ushort4 o;
    o.x = f2bf(v.x); o.y = f2bf(v.y); o.z = f2bf(v.z); o.w = f2bf(v.w);
    *(ushort4*)(hb0 + i * 4) = o;
  } else if (b < 16480) {
    // weight transpose + convert + k-chunked layout: Wt[mat][k0/32][n][k%32]
    int bb = b - 16384;                 // 96 = 6 mats x 16 tiles of 64x64
    int mat = bb >> 4, tile = bb & 15;
    int tr = (tile >> 2) * 64, tc = (tile & 3) * 64;   // tr = k-range, tc = n-range
    const float* src = (mat < 3) ? (gw1 + (size_t)mat * 65536) : (gw2 + (size_t)(mat - 3) * 65536);
#pragma unroll
    for (int i = 0; i < 4; i++) {
      int c = t + i * 256;              // 1024 float4 chunks
      int row = c >> 4, c4 = (c & 15) * 4;
      float4 v = *(const float4*)(src + (size_t)(tr + row) * 256 + tc + c4);
      sh[row][c4] = v.x; sh[row][c4 + 1] = v.y; sh[row][c4 + 2] = v.z; sh[row][c4 + 3] = v.w;
    }
    __syncthreads();
#pragma unroll
    for (int i = 0; i < 2; i++) {
      int c = t + i * 256;              // 512 chunks of 8 bf16
      int n = c >> 3, kc = (c & 7) * 8; // n local, k local (within 64x64 tile)
      unsigned short e[8];
#pragma unroll
      for (int j = 0; j < 8; j++) e[j] = f2bf(sh[kc + j][n]);
      uint4 o;
      o.x = e[0] | ((unsigned)e[1] << 16);
      o.y = e[2] | ((unsigned)e[3] << 16);
      o.z = e[4] | ((unsigned)e[5] << 16);
      o.w = e[6] | ((unsigned)e[7] << 16);
      int kg = tr + kc;                 // global k, 8-aligned
      size_t idx = (size_t)mat * 65536 + (size_t)(kg >> 5) * 8192 + (size_t)(tc + n) * 32 + (kg & 31);
      *(uint4*)(Wt + idx) = o;
    }
  } else {
    // one-pass CSR build: slot-append into fixed-capacity [node][64] ushort buckets
    int bb = b - 16480;                 // 4096
    int side = bb >> 11;
    int e = (bb & 2047) * 256 + t;
    const int* ei = (side ? e2 : e1);
    int s = ei[e], d = ei[NEDGE + e];
    int slot = atomicAdd(&cnt[side * NNODE + d], 1);
    if (slot < 64)
      srcs64[(((size_t)side * NNODE + d) << 6) + slot] = (unsigned short)s;
  }
}

// ---------------- fused layer: gather(+BN) -> GEMM1(relu) -> GEMM2 + stats ----------------
// grid 512 (2 sides x 256 row-blocks of 128), 512 thr = 8 waves (2m x 4n), wave tile 64x64.
// LDS 80KB: sA/sA2 [128][512B] at [0,64K), sW [256][64B] (k-chunk 32) at [64K,80K);
// red (4KB) aliases sW after phase 2. -> 2 blocks/CU.
template <bool BN>
__global__ __launch_bounds__(512, 4) void k_layer(
    const unsigned short* __restrict__ x,      // [2N][256] prev features
    const int* __restrict__ cnt,               // [2][NNODE] degrees
    const unsigned short* __restrict__ srcs64, // [2][NNODE][64] source ids
    const float* __restrict__ pstats,          // [2][2][256] prev layer (BN only)
    const float* __restrict__ pgamma, const float* __restrict__ pbeta,
    const unsigned short* __restrict__ w1t,    // chunked [8][256][32] bf16
    const unsigned short* __restrict__ w2t,
    const float* __restrict__ b1, const float* __restrict__ b2,
    float* __restrict__ stats,                 // [2][2][256] this layer
    unsigned short* __restrict__ hout) {
  __shared__ __align__(16) char smem[81920];
  char* sA = smem;                 // [128][512B] swizzled bf16
  char* sA2 = smem;                // alias
  char* sW = smem + 65536;         // [256][64B] swizzled W k-chunk
  float2* red = (float2*)(smem + 65536);   // alias of sW, used after phase 2
  int tid = threadIdx.x;
  int lane = tid & 63, wid = tid >> 6;
  int wm = wid & 1, wn = wid >> 1;
  int q = lane >> 4, r = lane & 15;
  const int swA = (r & 7) << 4;
  const int swW = ((r >> 1) & 3) << 4;
  int b = blockIdx.x;
  int side = b >> 8;
  size_t grow0 = (size_t)side * NNODE + (size_t)(b & 255) * 128;

  auto stageW = [&](const unsigned short* wsrc, int k0) {
    const unsigned short* basep = wsrc + (size_t)(k0 >> 5) * 8192;   // 16KB linear chunk
#pragma unroll
    for (int it = 0; it < 2; it++) {
      int c = tid + it * 512;            // 1024 float4 chunks
      int row = c >> 2, ch = c & 3;
      float4 v = *(const float4*)(basep + (size_t)c * 8);
      *(float4*)(sW + row * 64 + ((ch * 16) ^ (((row >> 1) & 3) << 4))) = v;
    }
  };

  stageW(w1t, 0);   // hoisted: loads overlap gather

  // ============ gather phase: aggregate 128 rows into sA ============
  {
    int hw = tid >> 5, sub = tid & 31;   // half-wave owns 8 node rows
    float sc[8], shf[8];
    if (BN) {
      int c0 = sub * 8;
      const float* cs = pstats + side * 512;
      const float invn = 1.f / 32768.f;
#pragma unroll
      for (int j = 0; j < 8; j++) {
        float mu = cs[c0 + j] * invn;
        float var = cs[256 + c0 + j] * invn - mu * mu;
        float s = pgamma[c0 + j] * rsqrtf(var + 1e-5f);
        sc[j] = s; shf[j] = pbeta[c0 + j] - mu * s;
      }
    }
    const uint4* X = (const uint4*)x;    // 32 uint4 per row
    size_t rbase = (size_t)side * NNODE;
    const int* degs = cnt + side * NNODE;
    const unsigned short* sr = srcs64 + ((size_t)side * NNODE << 6);
    int nbase = (int)(b & 255) * 128;

#pragma unroll 1
    for (int nn = 0; nn < 8; nn++) {
      int lrow = hw * 8 + nn;
      int n = nbase + lrow;
      float a[8];
#pragma unroll
      for (int j = 0; j < 8; j++) a[j] = 0.f;
      auto acc8 = [&](uint4 u, float w) {
        unsigned uu[4] = {u.x, u.y, u.z, u.w};
#pragma unroll
        for (int j = 0; j < 4; j++) {
          float lo = __uint_as_float(uu[j] << 16);
          float hi = __uint_as_float(uu[j] & 0xFFFF0000u);
          if (BN) {
            lo = fmaxf(fmaf(lo, sc[2 * j], shf[2 * j]), 0.f);
            hi = fmaxf(fmaf(hi, sc[2 * j + 1], shf[2 * j + 1]), 0.f);
          }
          a[2 * j] = fmaf(lo, w, a[2 * j]);
          a[2 * j + 1] = fmaf(hi, w, a[2 * j + 1]);
        }
      };
      acc8(X[(rbase + n) * 32 + sub], 2.f);
      int e = n << 6, ee = (n << 6) + degs[n];
      for (; e + 3 < ee; e += 4) {
        int i0 = sr[e], i1 = sr[e + 1], i2 = sr[e + 2], i3 = sr[e + 3];
        uint4 u0 = X[(rbase + i0) * 32 + sub];
        uint4 u1 = X[(rbase + i1) * 32 + sub];
        uint4 u2 = X[(rbase + i2) * 32 + sub];
        uint4 u3 = X[(rbase + i3) * 32 + sub];
        acc8(u0, 1.f); acc8(u1, 1.f); acc8(u2, 1.f); acc8(u3, 1.f);
      }
      for (; e < ee; e++) acc8(X[(rbase + sr[e]) * 32 + sub], 1.f);
      uint4 o;
      o.x = packbf(a[0], a[1]); o.y = packbf(a[2], a[3]);
      o.z = packbf(a[4], a[5]); o.w = packbf(a[6], a[7]);
      *(uint4*)(sA + lrow * 512 + ((sub * 16) ^ ((lrow & 7) << 4))) = o;
    }
  }

  f32x4 acc[4][4];
#pragma unroll
  for (int mi = 0; mi < 4; mi++)
#pragma unroll
    for (int ni = 0; ni < 4; ni++) acc[mi][ni] = (f32x4){0.f, 0.f, 0.f, 0.f};

  __syncthreads();

  // ---- phase 1: C1 = A @ W1 ----
  for (int k0 = 0; k0 < 256; k0 += 32) {
    bf16x8 af[4], bfr[4];
    int cbA = (k0 * 2 + q * 16) ^ swA;
    int cbW = (q * 16) ^ swW;
#pragma unroll
    for (int mi = 0; mi < 4; mi++)
      af[mi] = *(const bf16x8*)(sA + (wm * 64 + mi * 16 + r) * 512 + cbA);
#pragma unroll
    for (int ni = 0; ni < 4; ni++)
      bfr[ni] = *(const bf16x8*)(sW + (wn * 64 + ni * 16 + r) * 64 + cbW);
#pragma unroll
    for (int mi = 0; mi < 4; mi++)
#pragma unroll
      for (int ni = 0; ni < 4; ni++)
        acc[mi][ni] = __builtin_amdgcn_mfma_f32_16x16x32_bf16(af[mi], bfr[ni], acc[mi][ni], 0, 0, 0);
    __syncthreads();
    if (k0 < 224) {
      stageW(w1t, k0 + 32);
      __syncthreads();
    }
  }

  // epilogue 1: bias + relu -> bf16 into sA2 (alias of sA; all reads done)
  float b1v[4];
#pragma unroll
  for (int ni = 0; ni < 4; ni++) b1v[ni] = b1[wn * 64 + ni * 16 + r];
#pragma unroll
  for (int mi = 0; mi < 4; mi++)
#pragma unroll
    for (int ni = 0; ni < 4; ni++)
#pragma unroll
      for (int j = 0; j < 4; j++) {
        float o = fmaxf(acc[mi][ni][j] + b1v[ni], 0.f);
        int rowc = wm * 64 + mi * 16 + q * 4 + j;
        int colc = wn * 64 + ni * 16 + r;
        *(unsigned short*)(sA2 + rowc * 512 + ((colc * 2) ^ (((q * 4 + j) & 7) << 4))) = f2bf(o);
      }
#pragma unroll
  for (int mi = 0; mi < 4; mi++)
#pragma unroll
    for (int ni = 0; ni < 4; ni++) acc[mi][ni] = (f32x4){0.f, 0.f, 0.f, 0.f};
  stageW(w2t, 0);
  __syncthreads();

  // ---- phase 2: C2 = relu(C1) @ W2 ----
  for (int k0 = 0; k0 < 256; k0 += 32) {
    bf16x8 af[4], bfr[4];
    int cbA = (k0 * 2 + q * 16) ^ swA;
    int cbW = (q * 16) ^ swW;
#pragma unroll
    for (int mi = 0; mi < 4; mi++)
      af[mi] = *(const bf16x8*)(sA2 + (wm * 64 + mi * 16 + r) * 512 + cbA);
#pragma unroll
    for (int ni = 0; ni < 4; ni++)
      bfr[ni] = *(const bf16x8*)(sW + (wn * 64 + ni * 16 + r) * 64 + cbW);
#pragma unroll
    for (int mi = 0; mi < 4; mi++)
#pragma unroll
      for (int ni = 0; ni < 4; ni++)
        acc[mi][ni] = __builtin_amdgcn_mfma_f32_16x16x32_bf16(af[mi], bfr[ni], acc[mi][ni], 0, 0, 0);
    __syncthreads();
    if (k0 < 224) {
      stageW(w2t, k0 + 32);
      __syncthreads();
    }
  }

  // epilogue 2: bias, BN stats (shfl + red in sW region + atomics), bf16 out via sA2
  float b2v[4];
#pragma unroll
  for (int ni = 0; ni < 4; ni++) b2v[ni] = b2[wn * 64 + ni * 16 + r];
#pragma unroll
  for (int ni = 0; ni < 4; ni++) {
    float ss = 0.f, sq = 0.f;
#pragma unroll
    for (int mi = 0; mi < 4; mi++)
#pragma unroll
      for (int j = 0; j < 4; j++) {
        float o = acc[mi][ni][j] + b2v[ni];
        acc[mi][ni][j] = o;
        ss += o; sq += o * o;
      }
    ss += __shfl_xor(ss, 16, 64); ss += __shfl_xor(ss, 32, 64);
    sq += __shfl_xor(sq, 16, 64); sq += __shfl_xor(sq, 32, 64);
    if (q == 0) {
      float2 w; w.x = ss; w.y = sq;
      red[(wn * 64 + ni * 16 + r) * 2 + wm] = w;   // sW dead after phase 2 (last sync above)
    }
  }
#pragma unroll
  for (int mi = 0; mi < 4; mi++)
#pragma unroll
    for (int ni = 0; ni < 4; ni++)
#pragma unroll
      for (int j = 0; j < 4; j++) {
        int rowc = wm * 64 + mi * 16 + q * 4 + j;
        int colc = wn * 64 + ni * 16 + r;
        *(unsigned short*)(sA2 + rowc * 512 + ((colc * 2) ^ (((q * 4 + j) & 7) << 4))) =
            f2bf(acc[mi][ni][j]);
      }
  __syncthreads();
  float* cs = stats + side * 512;
  if (tid < 256) {
    float2 a = red[tid * 2], c2 = red[tid * 2 + 1];
    atomicAdd(&cs[tid], a.x + c2.x);
    atomicAdd(&cs[256 + tid], a.y + c2.y);
  }
  for (int c = tid; c < 4096; c += 512) {   // 128 rows x 32 chunks of 16B
    int row = c >> 5, cb = (c & 31) * 16;
    float4 v = *(const float4*)(sA2 + row * 512 + (cb ^ ((row & 7) << 4)));
    *(float4*)(hout + (grow0 + row) * 256 + (c & 31) * 8) = v;
  }
}

// ---------------- per-graph sum of relu(bn(h)) ----------------
__global__ __launch_bounds__(256) void k_gsum(
    const unsigned short* __restrict__ h, const float* __restrict__ stats,
    const float* __restrict__ gamma, const float* __restrict__ beta,
    float* __restrict__ sg) {
  int b = blockIdx.x;            // 256 = 2 sides x 128 graphs
  int side = b >> 7, g = b & 127;
  int t = threadIdx.x;
  int c0 = (t & 63) * 4, rg = t >> 6;
  const float* cs = stats + side * 512;
  float sc[4], sh_[4];
#pragma unroll
  for (int j = 0; j < 4; j++) {
    float mu = cs[c0 + j] * (1.f / 32768.f);
    float var = cs[256 + c0 + j] * (1.f / 32768.f) - mu * mu;
    float s = gamma[c0 + j] * rsqrtf(var + 1e-5f);
    sc[j] = s; sh_[j] = beta[c0 + j] - mu * s;
  }
  size_t base = (size_t)side * NNODE + (size_t)g * 256;
  float acc = 0.f;
  for (int k = 0; k < 64; k++) {
    int row = rg + k * 4;
    ushort4 u = *(const ushort4*)(h + (base + row) * 256 + c0);
    acc += fmaxf(fmaf(bf2f(u.x), sc[0], sh_[0]), 0.f);
    acc += fmaxf(fmaf(bf2f(u.y), sc[1], sh_[1]), 0.f);
    acc += fmaxf(fmaf(bf2f(u.z), sc[2], sh_[2]), 0.f);
    acc += fmaxf(fmaf(bf2f(u.w), sc[3], sh_[3]), 0.f);
  }
  __shared__ float red[256];
  red[t] = acc;
  __syncthreads();
  if (t < 64) {
    float s = red[t] + red[t + 64] + red[t + 128] + red[t + 192];
#pragma unroll
    for (int m = 1; m < 64; m <<= 1) s += __shfl_xor(s, m, 64);
    if (t == 0) sg[b] = s;
  }
}

// ---------------- final: p = sg1 - sg2, min-max normalize, exp(-p) ----------------
__global__ void k_final(const float* __restrict__ sg1, const float* __restrict__ sg2,
                        float* __restrict__ out) {
  int t = threadIdx.x;   // 64 threads
  float a = sg1[t] - sg2[t];
  float b = sg1[t + 64] - sg2[t + 64];
  float mn = fminf(a, b), mx = fmaxf(a, b);
#pragma unroll
  for (int msk = 1; msk < 64; msk <<= 1) {
    mn = fminf(mn, __shfl_xor(mn, msk, 64));
    mx = fmaxf(mx, __shfl_xor(mx, msk, 64));
  }
  float inv = 1.0f / (mx - mn);
  out[t] = __expf(-(a - mn) * inv);
  out[t + 64] = __expf(-(b - mn) * inv);
}

// ---------------- host ----------------
extern "C" void kernel_launch(void* const* d_in, const int* in_sizes, int n_in,
                              void* d_out, int out_size, void* d_ws, size_t ws_size,
                              hipStream_t stream) {
  (void)in_sizes; (void)n_in; (void)out_size; (void)ws_size;
  const float* f1 = (const float*)d_in[0];
  const float* f2 = (const float*)d_in[1];
  const int* e1 = (const int*)d_in[2];
  const int* e2 = (const int*)d_in[3];
  const float* gw1 = (const float*)d_in[5];
  const float* gb1 = (const float*)d_in[6];
  const float* gw2 = (const float*)d_in[7];
  const float* gb2 = (const float*)d_in[8];
  const float* gga = (const float*)d_in[9];
  const float* gbe = (const float*)d_in[10];
  float* out = (float*)d_out;

  char* ws = (char*)d_ws;
  size_t o = 0;
  auto alloc = [&](size_t bytes) { void* p = ws + o; o += (bytes + 255) & ~(size_t)255; return p; };
  unsigned short* hb0 = (unsigned short*)alloc(2ull * NNODE * 256 * 2);
  unsigned short* hb1 = (unsigned short*)alloc(2ull * NNODE * 256 * 2);
  unsigned short* Wt = (unsigned short*)alloc(6ull * 65536 * 2);
  float* stats = (float*)alloc(3 * 1024 * 4);      // [layer][side][{sum,sq}][256]
  float* sg = (float*)alloc(256 * 4);
  int* cnt = (int*)alloc(2 * NNODE * 4);
  unsigned short* srcs64 = (unsigned short*)alloc(2ull * NNODE * 64 * 2);   // 8 MB

  (void)hipMemsetAsync(stats, 0, 3 * 1024 * 4, stream);
  (void)hipMemsetAsync(cnt, 0, 2 * NNODE * 4, stream);

  k_prep<<<20576, 256, 0, stream>>>(f1, f2, hb0, gw1, gw2, Wt, e1, e2, cnt, srcs64);

  unsigned short* hb[2] = {hb0, hb1};
  for (int l = 0; l < 3; l++) {
    unsigned short* xin = hb[l & 1];
    unsigned short* hout = hb[1 - (l & 1)];
    if (l == 0)
      k_layer<false><<<512, 512, 0, stream>>>(
          xin, cnt, srcs64, nullptr, nullptr, nullptr,
          Wt + (size_t)l * 65536, Wt + (size_t)(3 + l) * 65536,
          gb1 + l * 256, gb2 + l * 256, stats + l * 1024, hout);
    else
      k_layer<true><<<512, 512, 0, stream>>>(
          xin, cnt, srcs64, stats + (l - 1) * 1024, gga + (l - 1) * 256, gbe + (l - 1) * 256,
          Wt + (size_t)l * 65536, Wt + (size_t)(3 + l) * 65536,
          gb1 + l * 256, gb2 + l * 256, stats + l * 1024, hout);
  }

  k_gsum<<<256, 256, 0, stream>>>(hb1, stats + 2 * 1024, gga + 512, gbe + 512, sg);
  k_final<<<1, 64, 0, stream>>>(sg, sg + 128, out);
}

// Round 12
// 422.205 us; speedup vs baseline: 1.3550x; 1.0169x over previous
//
#include <hip/hip_runtime.h>

// GSModel pipeline, round 12.
//  - p_b = sum(g1_b) - sum(g2_b) identity (sinkhorn colsum==1) — scores path removed.
//  - bf16 storage; MFMA 16x16x32 bf16; fused gather+GEMM1+GEMM2 k_layer.
//  - One-pass slot-CSR (round 11).
//  - NEW (a): degree-sorted row assignment in gather — k_sortdeg pre-sorts each
//    128-row group by degree; at step nn half-wave hw takes perm[nn*16+hw] so all
//    16 half-waves carry near-equal work between barriers (kills the Poisson
//    max-of-16 imbalance, ~15% of gather time). Pure reorder: bit-identical math.
//  - NEW (b): B-operand (W) read directly from global (L2-resident 128KB, chunked
//    layout) — deletes sW staging and ALL inner GEMM barriers (32 -> 5 per tile).
//    LDS 68KB, 2 blocks/CU, launch_bounds(512,4) caps VGPR at 128.

constexpr int NNODE = 32768;
constexpr int NEDGE = 524288;

typedef __attribute__((ext_vector_type(8))) short bf16x8;
typedef __attribute__((ext_vector_type(4))) float f32x4;

__device__ __forceinline__ float bf2f(unsigned short u) {
  return __uint_as_float((unsigned)u << 16);
}
__device__ __forceinline__ unsigned short f2bf(float f) {
  unsigned u = __float_as_uint(f);
  return (unsigned short)((u + 0x7FFFu + ((u >> 16) & 1u)) >> 16);
}
__device__ __forceinline__ unsigned packbf(float a, float b) {
  return (unsigned)f2bf(a) | ((unsigned)f2bf(b) << 16);
}

// ---------------- fused prep: conv (16384) | wprep (96) | CSR build (4096) ----------------
__global__ __launch_bounds__(256) void k_prep(
    const float* __restrict__ f1, const float* __restrict__ f2,
    unsigned short* __restrict__ hb0,
    const float* __restrict__ gw1, const float* __restrict__ gw2,
    unsigned short* __restrict__ Wt,
    const int* __restrict__ e1, const int* __restrict__ e2,
    int* __restrict__ cnt, unsigned short* __restrict__ srcs64) {
  __shared__ float sh[64][65];
  int b = blockIdx.x, t = threadIdx.x;
  if (b < 16384) {
    // f32 -> bf16 feature convert
    size_t i = (size_t)b * 256 + t;     // 4,194,304 chunks of 4
    const float* src = (i < 2097152) ? (f1 + i * 4) : (f2 + (i - 2097152) * 4);
    float4 v = *(const float4*)src;
    ushort4 o;
    o.x = f2bf(v.x); o.y = f2bf(v.y); o.z = f2bf(v.z); o.w = f2bf(v.w);
    *(ushort4*)(hb0 + i * 4) = o;
  } else if (b < 16480) {
    // weight transpose + convert + k-chunked layout: Wt[mat][k0/32][n][k%32]
    int bb = b - 16384;                 // 96 = 6 mats x 16 tiles of 64x64
    int mat = bb >> 4, tile = bb & 15;
    int tr = (tile >> 2) * 64, tc = (tile & 3) * 64;   // tr = k-range, tc = n-range
    const float* src = (mat < 3) ? (gw1 + (size_t)mat * 65536) : (gw2 + (size_t)(mat - 3) * 65536);
#pragma unroll
    for (int i = 0; i < 4; i++) {
      int c = t + i * 256;              // 1024 float4 chunks
      int row = c >> 4, c4 = (c & 15) * 4;
      float4 v = *(const float4*)(src + (size_t)(tr + row) * 256 + tc + c4);
      sh[row][c4] = v.x; sh[row][c4 + 1] = v.y; sh[row][c4 + 2] = v.z; sh[row][c4 + 3] = v.w;
    }
    __syncthreads();
#pragma unroll
    for (int i = 0; i < 2; i++) {
      int c = t + i * 256;              // 512 chunks of 8 bf16
      int n = c >> 3, kc = (c & 7) * 8; // n local, k local (within 64x64 tile)
      unsigned short e[8];
#pragma unroll
      for (int j = 0; j < 8; j++) e[j] = f2bf(sh[kc + j][n]);
      uint4 o;
      o.x = e[0] | ((unsigned)e[1] << 16);
      o.y = e[2] | ((unsigned)e[3] << 16);
      o.z = e[4] | ((unsigned)e[5] << 16);
      o.w = e[6] | ((unsigned)e[7] << 16);
      int kg = tr + kc;                 // global k, 8-aligned
      size_t idx = (size_t)mat * 65536 + (size_t)(kg >> 5) * 8192 + (size_t)(tc + n) * 32 + (kg & 31);
      *(uint4*)(Wt + idx) = o;
    }
  } else {
    // one-pass CSR build: slot-append into fixed-capacity [node][64] ushort buckets
    int bb = b - 16480;                 // 4096
    int side = bb >> 11;
    int e = (bb & 2047) * 256 + t;
    const int* ei = (side ? e2 : e1);
    int s = ei[e], d = ei[NEDGE + e];
    int slot = atomicAdd(&cnt[side * NNODE + d], 1);
    if (slot < 64)
      srcs64[(((size_t)side * NNODE + d) << 6) + slot] = (unsigned short)s;
  }
}

// ---------------- per-group degree sort: perm[i] = row index of i-th smallest deg ----------------
__global__ __launch_bounds__(128) void k_sortdeg(const int* __restrict__ cnt,
                                                 unsigned char* __restrict__ perm) {
  __shared__ int s[128];
  int g = blockIdx.x;                   // 512 = 2 sides x 256 groups
  int side = g >> 8, grp = g & 255;
  int t = threadIdx.x;
  int deg = cnt[side * NNODE + grp * 128 + t];
  s[t] = (deg << 8) | t;
  __syncthreads();
  for (int k = 2; k <= 128; k <<= 1)
    for (int j = k >> 1; j > 0; j >>= 1) {
      int ixj = t ^ j;
      if (ixj > t) {
        int a = s[t], b2 = s[ixj];
        bool up = ((t & k) == 0);
        if ((a > b2) == up) { s[t] = b2; s[ixj] = a; }
      }
      __syncthreads();
    }
  perm[(size_t)side * NNODE + grp * 128 + t] = (unsigned char)(s[t] & 255);
}

// ---------------- fused layer: gather(+BN) -> GEMM1(relu) -> GEMM2 + stats ----------------
// grid 512 (2 sides x 256 row-blocks of 128), 512 thr = 8 waves (2m x 4n), wave tile 64x64.
// LDS 68KB: sA/sA2 [128][512B] at [0,64K), red 4KB at [64K,68K). 2 blocks/CU.
// W read directly from global (L2-resident, chunked [8][256][32]) — no inner barriers.
template <bool BN>
__global__ __launch_bounds__(512, 4) void k_layer(
    const unsigned short* __restrict__ x,      // [2N][256] prev features
    const int* __restrict__ cnt,               // [2][NNODE] degrees
    const unsigned short* __restrict__ srcs64, // [2][NNODE][64] source ids
    const unsigned char* __restrict__ perm,    // [2][NNODE] degree-sorted row order
    const float* __restrict__ pstats,          // [2][2][256] prev layer (BN only)
    const float* __restrict__ pgamma, const float* __restrict__ pbeta,
    const unsigned short* __restrict__ w1t,    // chunked [8][256][32] bf16
    const unsigned short* __restrict__ w2t,
    const float* __restrict__ b1, const float* __restrict__ b2,
    float* __restrict__ stats,                 // [2][2][256] this layer
    unsigned short* __restrict__ hout) {
  __shared__ __align__(16) char smem[69632];
  char* sA = smem;                 // [128][512B] swizzled bf16
  char* sA2 = smem;                // alias
  float2* red = (float2*)(smem + 65536);   // [256][2]
  int tid = threadIdx.x;
  int lane = tid & 63, wid = tid >> 6;
  int wm = wid & 1, wn = wid >> 1;
  int q = lane >> 4, r = lane & 15;
  const int swA = (r & 7) << 4;
  int b = blockIdx.x;
  int side = b >> 8;
  size_t grow0 = (size_t)side * NNODE + (size_t)(b & 255) * 128;

  // ============ gather phase: aggregate 128 rows into sA (degree-balanced order) ============
  {
    int hw = tid >> 5, sub = tid & 31;   // half-wave owns 8 rows via perm
    float sc[8], shf[8];
    if (BN) {
      int c0 = sub * 8;
      const float* cs = pstats + side * 512;
      const float invn = 1.f / 32768.f;
#pragma unroll
      for (int j = 0; j < 8; j++) {
        float mu = cs[c0 + j] * invn;
        float var = cs[256 + c0 + j] * invn - mu * mu;
        float s = pgamma[c0 + j] * rsqrtf(var + 1e-5f);
        sc[j] = s; shf[j] = pbeta[c0 + j] - mu * s;
      }
    }
    const uint4* X = (const uint4*)x;    // 32 uint4 per row
    size_t rbase = (size_t)side * NNODE;
    const int* degs = cnt + side * NNODE;
    const unsigned short* sr = srcs64 + ((size_t)side * NNODE << 6);
    const unsigned char* pg = perm + (size_t)side * NNODE + (size_t)(b & 255) * 128;
    int nbase = (int)(b & 255) * 128;

#pragma unroll 1
    for (int nn = 0; nn < 8; nn++) {
      int lrow = pg[nn * 16 + hw];       // degree-sorted: all 16 half-waves balanced
      int n = nbase + lrow;
      float a[8];
#pragma unroll
      for (int j = 0; j < 8; j++) a[j] = 0.f;
      auto acc8 = [&](uint4 u, float w) {
        unsigned uu[4] = {u.x, u.y, u.z, u.w};
#pragma unroll
        for (int j = 0; j < 4; j++) {
          float lo = __uint_as_float(uu[j] << 16);
          float hi = __uint_as_float(uu[j] & 0xFFFF0000u);
          if (BN) {
            lo = fmaxf(fmaf(lo, sc[2 * j], shf[2 * j]), 0.f);
            hi = fmaxf(fmaf(hi, sc[2 * j + 1], shf[2 * j + 1]), 0.f);
          }
          a[2 * j] = fmaf(lo, w, a[2 * j]);
          a[2 * j + 1] = fmaf(hi, w, a[2 * j + 1]);
        }
      };
      acc8(X[(rbase + n) * 32 + sub], 2.f);
      int e = n << 6, ee = (n << 6) + degs[n];
      for (; e + 3 < ee; e += 4) {
        int i0 = sr[e], i1 = sr[e + 1], i2 = sr[e + 2], i3 = sr[e + 3];
        uint4 u0 = X[(rbase + i0) * 32 + sub];
        uint4 u1 = X[(rbase + i1) * 32 + sub];
        uint4 u2 = X[(rbase + i2) * 32 + sub];
        uint4 u3 = X[(rbase + i3) * 32 + sub];
        acc8(u0, 1.f); acc8(u1, 1.f); acc8(u2, 1.f); acc8(u3, 1.f);
      }
      for (; e < ee; e++) acc8(X[(rbase + sr[e]) * 32 + sub], 1.f);
      uint4 o;
      o.x = packbf(a[0], a[1]); o.y = packbf(a[2], a[3]);
      o.z = packbf(a[4], a[5]); o.w = packbf(a[6], a[7]);
      *(uint4*)(sA + lrow * 512 + ((sub * 16) ^ ((lrow & 7) << 4))) = o;
    }
  }

  f32x4 acc[4][4];
#pragma unroll
  for (int mi = 0; mi < 4; mi++)
#pragma unroll
    for (int ni = 0; ni < 4; ni++) acc[mi][ni] = (f32x4){0.f, 0.f, 0.f, 0.f};

  __syncthreads();

  // ---- phase 1: C1 = A @ W1 (B direct from global, no barriers) ----
#pragma unroll 2
  for (int k0 = 0; k0 < 256; k0 += 32) {
    bf16x8 af[4], bfr[4];
    int cbA = (k0 * 2 + q * 16) ^ swA;
    const unsigned short* wb = w1t + (size_t)(k0 >> 5) * 8192 + q * 8;
#pragma unroll
    for (int ni = 0; ni < 4; ni++)
      bfr[ni] = *(const bf16x8*)(wb + (size_t)(wn * 64 + ni * 16 + r) * 32);
#pragma unroll
    for (int mi = 0; mi < 4; mi++)
      af[mi] = *(const bf16x8*)(sA + (wm * 64 + mi * 16 + r) * 512 + cbA);
#pragma unroll
    for (int mi = 0; mi < 4; mi++)
#pragma unroll
      for (int ni = 0; ni < 4; ni++)
        acc[mi][ni] = __builtin_amdgcn_mfma_f32_16x16x32_bf16(af[mi], bfr[ni], acc[mi][ni], 0, 0, 0);
  }
  __syncthreads();   // all GEMM1 reads of sA complete

  // epilogue 1: bias + relu -> bf16 into sA2 (alias of sA)
  float b1v[4];
#pragma unroll
  for (int ni = 0; ni < 4; ni++) b1v[ni] = b1[wn * 64 + ni * 16 + r];
#pragma unroll
  for (int mi = 0; mi < 4; mi++)
#pragma unroll
    for (int ni = 0; ni < 4; ni++)
#pragma unroll
      for (int j = 0; j < 4; j++) {
        float o = fmaxf(acc[mi][ni][j] + b1v[ni], 0.f);
        int rowc = wm * 64 + mi * 16 + q * 4 + j;
        int colc = wn * 64 + ni * 16 + r;
        *(unsigned short*)(sA2 + rowc * 512 + ((colc * 2) ^ (((q * 4 + j) & 7) << 4))) = f2bf(o);
      }
#pragma unroll
  for (int mi = 0; mi < 4; mi++)
#pragma unroll
    for (int ni = 0; ni < 4; ni++) acc[mi][ni] = (f32x4){0.f, 0.f, 0.f, 0.f};
  __syncthreads();   // C1 fully written

  // ---- phase 2: C2 = relu(C1) @ W2 (B direct from global, no barriers) ----
#pragma unroll 2
  for (int k0 = 0; k0 < 256; k0 += 32) {
    bf16x8 af[4], bfr[4];
    int cbA = (k0 * 2 + q * 16) ^ swA;
    const unsigned short* wb = w2t + (size_t)(k0 >> 5) * 8192 + q * 8;
#pragma unroll
    for (int ni = 0; ni < 4; ni++)
      bfr[ni] = *(const bf16x8*)(wb + (size_t)(wn * 64 + ni * 16 + r) * 32);
#pragma unroll
    for (int mi = 0; mi < 4; mi++)
      af[mi] = *(const bf16x8*)(sA2 + (wm * 64 + mi * 16 + r) * 512 + cbA);
#pragma unroll
    for (int mi = 0; mi < 4; mi++)
#pragma unroll
      for (int ni = 0; ni < 4; ni++)
        acc[mi][ni] = __builtin_amdgcn_mfma_f32_16x16x32_bf16(af[mi], bfr[ni], acc[mi][ni], 0, 0, 0);
  }
  __syncthreads();   // all GEMM2 reads of sA2 complete

  // epilogue 2: bias, BN stats (shfl + red + atomics), bf16 out via sA2
  float b2v[4];
#pragma unroll
  for (int ni = 0; ni < 4; ni++) b2v[ni] = b2[wn * 64 + ni * 16 + r];
#pragma unroll
  for (int ni = 0; ni < 4; ni++) {
    float ss = 0.f, sq = 0.f;
#pragma unroll
    for (int mi = 0; mi < 4; mi++)
#pragma unroll
      for (int j = 0; j < 4; j++) {
        float o = acc[mi][ni][j] + b2v[ni];
        acc[mi][ni][j] = o;
        ss += o; sq += o * o;
      }
    ss += __shfl_xor(ss, 16, 64); ss += __shfl_xor(ss, 32, 64);
    sq += __shfl_xor(sq, 16, 64); sq += __shfl_xor(sq, 32, 64);
    if (q == 0) {
      float2 w; w.x = ss; w.y = sq;
      red[(wn * 64 + ni * 16 + r) * 2 + wm] = w;
    }
  }
#pragma unroll
  for (int mi = 0; mi < 4; mi++)
#pragma unroll
    for (int ni = 0; ni < 4; ni++)
#pragma unroll
      for (int j = 0; j < 4; j++) {
        int rowc = wm * 64 + mi * 16 + q * 4 + j;
        int colc = wn * 64 + ni * 16 + r;
        *(unsigned short*)(sA2 + rowc * 512 + ((colc * 2) ^ (((q * 4 + j) & 7) << 4))) =
            f2bf(acc[mi][ni][j]);
      }
  __syncthreads();
  float* cs = stats + side * 512;
  if (tid < 256) {
    float2 a = red[tid * 2], c2 = red[tid * 2 + 1];
    atomicAdd(&cs[tid], a.x + c2.x);
    atomicAdd(&cs[256 + tid], a.y + c2.y);
  }
  for (int c = tid; c < 4096; c += 512) {   // 128 rows x 32 chunks of 16B
    int row = c >> 5, cb = (c & 31) * 16;
    float4 v = *(const float4*)(sA2 + row * 512 + (cb ^ ((row & 7) << 4)));
    *(float4*)(hout + (grow0 + row) * 256 + (c & 31) * 8) = v;
  }
}

// ---------------- per-graph sum of relu(bn(h)) ----------------
__global__ __launch_bounds__(256) void k_gsum(
    const unsigned short* __restrict__ h, const float* __restrict__ stats,
    const float* __restrict__ gamma, const float* __restrict__ beta,
    float* __restrict__ sg) {
  int b = blockIdx.x;            // 256 = 2 sides x 128 graphs
  int side = b >> 7, g = b & 127;
  int t = threadIdx.x;
  int c0 = (t & 63) * 4, rg = t >> 6;
  const float* cs = stats + side * 512;
  float sc[4], sh_[4];
#pragma unroll
  for (int j = 0; j < 4; j++) {
    float mu = cs[c0 + j] * (1.f / 32768.f);
    float var = cs[256 + c0 + j] * (1.f / 32768.f) - mu * mu;
    float s = gamma[c0 + j] * rsqrtf(var + 1e-5f);
    sc[j] = s; sh_[j] = beta[c0 + j] - mu * s;
  }
  size_t base = (size_t)side * NNODE + (size_t)g * 256;
  float acc = 0.f;
  for (int k = 0; k < 64; k++) {
    int row = rg + k * 4;
    ushort4 u = *(const ushort4*)(h + (base + row) * 256 + c0);
    acc += fmaxf(fmaf(bf2f(u.x), sc[0], sh_[0]), 0.f);
    acc += fmaxf(fmaf(bf2f(u.y), sc[1], sh_[1]), 0.f);
    acc += fmaxf(fmaf(bf2f(u.z), sc[2], sh_[2]), 0.f);
    acc += fmaxf(fmaf(bf2f(u.w), sc[3], sh_[3]), 0.f);
  }
  __shared__ float red[256];
  red[t] = acc;
  __syncthreads();
  if (t < 64) {
    float s = red[t] + red[t + 64] + red[t + 128] + red[t + 192];
#pragma unroll
    for (int m = 1; m < 64; m <<= 1) s += __shfl_xor(s, m, 64);
    if (t == 0) sg[b] = s;
  }
}

// ---------------- final: p = sg1 - sg2, min-max normalize, exp(-p) ----------------
__global__ void k_final(const float* __restrict__ sg1, const float* __restrict__ sg2,
                        float* __restrict__ out) {
  int t = threadIdx.x;   // 64 threads
  float a = sg1[t] - sg2[t];
  float b = sg1[t + 64] - sg2[t + 64];
  float mn = fminf(a, b), mx = fmaxf(a, b);
#pragma unroll
  for (int msk = 1; msk < 64; msk <<= 1) {
    mn = fminf(mn, __shfl_xor(mn, msk, 64));
    mx = fmaxf(mx, __shfl_xor(mx, msk, 64));
  }
  float inv = 1.0f / (mx - mn);
  out[t] = __expf(-(a - mn) * inv);
  out[t + 64] = __expf(-(b - mn) * inv);
}

// ---------------- host ----------------
extern "C" void kernel_launch(void* const* d_in, const int* in_sizes, int n_in,
                              void* d_out, int out_size, void* d_ws, size_t ws_size,
                              hipStream_t stream) {
  (void)in_sizes; (void)n_in; (void)out_size; (void)ws_size;
  const float* f1 = (const float*)d_in[0];
  const float* f2 = (const float*)d_in[1];
  const int* e1 = (const int*)d_in[2];
  const int* e2 = (const int*)d_in[3];
  const float* gw1 = (const float*)d_in[5];
  const float* gb1 = (const float*)d_in[6];
  const float* gw2 = (const float*)d_in[7];
  const float* gb2 = (const float*)d_in[8];
  const float* gga = (const float*)d_in[9];
  const float* gbe = (const float*)d_in[10];
  float* out = (float*)d_out;

  char* ws = (char*)d_ws;
  size_t o = 0;
  auto alloc = [&](size_t bytes) { void* p = ws + o; o += (bytes + 255) & ~(size_t)255; return p; };
  unsigned short* hb0 = (unsigned short*)alloc(2ull * NNODE * 256 * 2);
  unsigned short* hb1 = (unsigned short*)alloc(2ull * NNODE * 256 * 2);
  unsigned short* Wt = (unsigned short*)alloc(6ull * 65536 * 2);
  float* stats = (float*)alloc(3 * 1024 * 4);      // [layer][side][{sum,sq}][256]
  float* sg = (float*)alloc(256 * 4);
  int* cnt = (int*)alloc(2 * NNODE * 4);
  unsigned short* srcs64 = (unsigned short*)alloc(2ull * NNODE * 64 * 2);   // 8 MB
  unsigned char* perm = (unsigned char*)alloc(2ull * NNODE);

  (void)hipMemsetAsync(stats, 0, 3 * 1024 * 4, stream);
  (void)hipMemsetAsync(cnt, 0, 2 * NNODE * 4, stream);

  k_prep<<<20576, 256, 0, stream>>>(f1, f2, hb0, gw1, gw2, Wt, e1, e2, cnt, srcs64);
  k_sortdeg<<<512, 128, 0, stream>>>(cnt, perm);

  unsigned short* hb[2] = {hb0, hb1};
  for (int l = 0; l < 3; l++) {
    unsigned short* xin = hb[l & 1];
    unsigned short* hout = hb[1 - (l & 1)];
    if (l == 0)
      k_layer<false><<<512, 512, 0, stream>>>(
          xin, cnt, srcs64, perm, nullptr, nullptr, nullptr,
          Wt + (size_t)l * 65536, Wt + (size_t)(3 + l) * 65536,
          gb1 + l * 256, gb2 + l * 256, stats + l * 1024, hout);
    else
      k_layer<true><<<512, 512, 0, stream>>>(
          xin, cnt, srcs64, perm, stats + (l - 1) * 1024, gga + (l - 1) * 256, gbe + (l - 1) * 256,
          Wt + (size_t)l * 65536, Wt + (size_t)(3 + l) * 65536,
          gb1 + l * 256, gb2 + l * 256, stats + l * 1024, hout);
  }

  k_gsum<<<256, 256, 0, stream>>>(hb1, stats + 2 * 1024, gga + 512, gbe + 512, sg);
  k_final<<<1, 64, 0, stream>>>(sg, sg + 128, out);
}